// Round 15
// baseline (1399.937 us; speedup 1.0000x reference)
//
#include <hip/hip_runtime.h>
#include <hip/hip_bf16.h>
#include <math.h>

typedef unsigned short u16;
typedef __attribute__((ext_vector_type(8))) short bf16x8;
typedef __attribute__((ext_vector_type(4))) float f32x4;
struct __align__(8) u16x4 { u16 x, y, z, w; };

constexpr int BB   = 2048;
constexpr int DF_  = 94;
constexpr int HH   = 376;
constexpr int LL   = 64;
constexpr int FIN  = 256;
constexpr float PADV = -999.0f;

static inline int cdiv(int a, int b) { return (a + b - 1) / b; }

__device__ __forceinline__ u16 f2bf(float v) {
    union { float f; unsigned u; } c; c.f = v;
    unsigned r = c.u + 0x7FFF + ((c.u >> 16) & 1);   // RNE
    return (u16)(r >> 16);
}
__device__ __forceinline__ float bf2f(u16 v) {
    union { unsigned u; float f; } c; c.u = ((unsigned)v) << 16;
    return c.f;
}
__device__ __forceinline__ void unpack8(uint4 v, float* t) {
    union { unsigned u; float f; } c;
    c.u = v.x << 16;          t[0] = c.f;
    c.u = v.x & 0xFFFF0000u;  t[1] = c.f;
    c.u = v.y << 16;          t[2] = c.f;
    c.u = v.y & 0xFFFF0000u;  t[3] = c.f;
    c.u = v.z << 16;          t[4] = c.f;
    c.u = v.z & 0xFFFF0000u;  t[5] = c.f;
    c.u = v.w << 16;          t[6] = c.f;
    c.u = v.w & 0xFFFF0000u;  t[7] = c.f;
}

// ---------------------------------------------------------------------------
// degree / CSR build
// ---------------------------------------------------------------------------
__global__ __launch_bounds__(256)
void zero_int_kernel(int* a, int n) {
    int i = blockIdx.x * 256 + threadIdx.x;
    if (i < n) a[i] = 0;
}

__global__ __launch_bounds__(256)
void count_deg_kernel(const int* __restrict__ col, int* deg, int E) {
    int e = blockIdx.x * 256 + threadIdx.x;
    if (e < E) atomicAdd(&deg[col[e]], 1);
}

__global__ __launch_bounds__(256)
void dinv_kernel(const int* __restrict__ deg, float* dinv, int N) {
    int i = blockIdx.x * 256 + threadIdx.x;
    if (i < N) dinv[i] = rsqrtf((float)(1 + deg[i]));
}

__global__ __launch_bounds__(1024)
void scan1_kernel(const int* __restrict__ deg, int N, int* __restrict__ rowptr,
                  int* __restrict__ bsum) {
    __shared__ int sh[1024];
    int t = threadIdx.x, base = blockIdx.x * 1024;
    int v = (base + t < N) ? deg[base + t] : 0;
    sh[t] = v; __syncthreads();
    for (int o = 1; o < 1024; o <<= 1) {
        int x = (t >= o) ? sh[t - o] : 0;
        __syncthreads();
        sh[t] += x;
        __syncthreads();
    }
    if (base + t < N) rowptr[base + t] = sh[t] - v;
    if (t == 1023) bsum[blockIdx.x] = sh[1023];
}

__global__ void scan2_kernel(int* bsum, int nb, int* rowptr, int N) {
    if (threadIdx.x == 0) {
        int s = 0;
        for (int i = 0; i < nb; ++i) { int v = bsum[i]; bsum[i] = s; s += v; }
        rowptr[N] = s;
    }
}

__global__ __launch_bounds__(1024)
void scan3_kernel(int* __restrict__ rowptr, int* __restrict__ cursor,
                  const int* __restrict__ bsum, int N) {
    int i = blockIdx.x * 1024 + threadIdx.x;
    if (i < N) {
        int v = rowptr[i] + bsum[blockIdx.x];
        rowptr[i] = v;
        cursor[i] = v;
    }
}

__global__ __launch_bounds__(256)
void fill_csr_kernel(const int* __restrict__ row, const int* __restrict__ col,
                     int* __restrict__ cursor, int* __restrict__ csr_src, int E) {
    int e = blockIdx.x * 256 + threadIdx.x;
    if (e < E) {
        int pos = atomicAdd(&cursor[col[e]], 1);
        csr_src[pos] = row[e];
    }
}

__global__ __launch_bounds__(1024)
void goff_kernel(const int* __restrict__ nn, int* __restrict__ goff, double* kl_acc) {
    __shared__ int sh[1024];
    __shared__ int carry;
    int t = threadIdx.x;
    if (t == 0) carry = 0;
    __syncthreads();
    for (int base = 0; base < BB; base += 1024) {
        int v = nn[base + t];
        sh[t] = v; __syncthreads();
        for (int o = 1; o < 1024; o <<= 1) {
            int x = (t >= o) ? sh[t - o] : 0;
            __syncthreads();
            sh[t] += x;
            __syncthreads();
        }
        goff[base + t] = carry + sh[t] - v;
        int tot = sh[1023];
        __syncthreads();
        if (t == 0) carry += tot;
        __syncthreads();
    }
    if (t == 0) { goff[BB] = carry; *kl_acc = 0.0; }
}

// ---------------------------------------------------------------------------
// merged pad-vector prep
// ---------------------------------------------------------------------------
__global__ __launch_bounds__(256)
void pads_kernel(const float* b1, const float* b2, const float* b3,
                 const float* seg, const float* mb1, const float* vb1,
                 float* b1p, float* b2p, float* b3p, float* segp, float* b768p) {
    int i = blockIdx.x * 256 + threadIdx.x;
    if (i < 192)            b1p[i] = (i < 188) ? b1[i] : 0.0f;
    else if (i < 480)  { int j = i - 192;  b2p[j]   = (j < 282) ? b2[j]  : 0.0f; }
    else if (i < 864)  { int j = i - 480;  b3p[j]   = (j < 376) ? b3[j]  : 0.0f; }
    else if (i < 1248) { int j = i - 864;  segp[j]  = (j < 376) ? seg[j] : 0.0f; }
    else if (i < 1632) { int j = i - 1248; b768p[j] = (j < 376) ? mb1[j] : 0.0f; }
    else if (i < 2016) { int j = i - 1632; b768p[384 + j] = (j < 376) ? vb1[j] : 0.0f; }
}

__global__ __launch_bounds__(256)
void init_bias_kernel(float* __restrict__ out, const float* __restrict__ bias,
                      size_t total, int F) {
    size_t idx = (size_t)blockIdx.x * 256 + threadIdx.x;
    if (idx < total) out[idx] = bias[idx % F];
}

__global__ __launch_bounds__(256)
void cast4_kernel(const float4* __restrict__ in, u16x4* __restrict__ out, int total4) {
    int idx = blockIdx.x * 256 + threadIdx.x;
    if (idx >= total4) return;
    float4 v = in[idx];
    u16x4 o; o.x = f2bf(v.x); o.y = f2bf(v.y); o.z = f2bf(v.z); o.w = f2bf(v.w);
    out[idx] = o;
}

// ---------------------------------------------------------------------------
// batched weight transpose+cast
// ---------------------------------------------------------------------------
constexpr int NJOBS = 10;
struct TJobs {
    const float* W[NJOBS];
    u16* out[NJOBS];
    int K[NJOBS], Nn[NJOBS], base[NJOBS], ktiles[NJOBS];
    int njobs;
};

__global__ __launch_bounds__(256)
void transpose_batch_kernel(TJobs jobs) {
    __shared__ float t[32][33];
    int tb = blockIdx.x;
    int j = 0;
    #pragma unroll
    for (int i = 1; i < NJOBS; ++i)
        if (i < jobs.njobs && tb >= jobs.base[i]) j = i;
    int rel = tb - jobs.base[j];
    int gk = (rel % jobs.ktiles[j]) * 32;
    int gn = (rel / jobs.ktiles[j]) * 32;
    const float* W = jobs.W[j];
    u16* out = jobs.out[j];
    int K = jobs.K[j], Nn = jobs.Nn[j];
    int Kpad = jobs.ktiles[j] * 32;

    int tx = threadIdx.x & 31, ty = threadIdx.x >> 5;
    #pragma unroll
    for (int r = 0; r < 4; ++r) {
        int row = gk + ty + r * 8, col = gn + tx;
        t[ty + r * 8][tx] = (row < K && col < Nn) ? W[(size_t)row * Nn + col] : 0.0f;
    }
    __syncthreads();
    #pragma unroll
    for (int r = 0; r < 4; ++r) {
        int n = gn + ty + r * 8, k = gk + tx;
        out[(size_t)n * Kpad + k] = f2bf(t[tx][ty + r * 8]);
    }
}

// ---------------------------------------------------------------------------
// aggregate-first GCN sparse step
// ---------------------------------------------------------------------------
template<int U, int G, bool F32IN>
__global__ __launch_bounds__(256)
void agg_kernel(const void* __restrict__ inp, const int* __restrict__ rowptr,
                const int* __restrict__ csr_src, const float* __restrict__ dinv,
                u16* __restrict__ out, int N) {
    constexpr int NPB = 256 / G;
    int u = threadIdx.x & (G - 1);
    int n = blockIdx.x * NPB + threadIdx.x / G;
    if (n >= N || u >= U) return;
    float di = dinv[n];
    float acc[8];
    if (F32IN) {
        const float* xr = (const float*)inp + (size_t)n * 94 + u * 8;
        #pragma unroll
        for (int j = 0; j < 8; ++j)
            acc[j] = (u * 8 + j < 94) ? di * xr[j] : 0.0f;
    } else {
        float t[8];
        unpack8(((const uint4*)inp)[(size_t)n * U + u], t);
        #pragma unroll
        for (int j = 0; j < 8; ++j) acc[j] = di * t[j];
    }
    int e0 = rowptr[n], e1 = rowptr[n + 1];
    for (int e = e0; e < e1; ++e) {
        int r = csr_src[e];
        float w = dinv[r];
        if (F32IN) {
            const float* rr = (const float*)inp + (size_t)r * 94 + u * 8;
            #pragma unroll
            for (int j = 0; j < 8; ++j)
                if (u * 8 + j < 94) acc[j] = fmaf(w, rr[j], acc[j]);
        } else {
            float t[8];
            unpack8(((const uint4*)inp)[(size_t)r * U + u], t);
            #pragma unroll
            for (int j = 0; j < 8; ++j) acc[j] = fmaf(w, t[j], acc[j]);
        }
    }
    unsigned w0 = (unsigned)f2bf(di * acc[0]) | ((unsigned)f2bf(di * acc[1]) << 16);
    unsigned w1 = (unsigned)f2bf(di * acc[2]) | ((unsigned)f2bf(di * acc[3]) << 16);
    unsigned w2 = (unsigned)f2bf(di * acc[4]) | ((unsigned)f2bf(di * acc[5]) << 16);
    unsigned w3 = (unsigned)f2bf(di * acc[6]) | ((unsigned)f2bf(di * acc[7]) << 16);
    ((uint4*)out)[(size_t)n * U + u] = make_uint4(w0, w1, w2, w3);
}

// ---------------------------------------------------------------------------
// A-panel-resident GEMM (layer GEMMs)
// MODE: 2 bf16 relu(v+bias), 7 L3 epilogue (a0b + dseq scatter)
// ---------------------------------------------------------------------------
template<int MODE, int KP>
__global__ __launch_bounds__(256)
void panel_gemm_kernel(const u16* __restrict__ A, const u16* __restrict__ BT,
                       const float* __restrict__ bias, void* __restrict__ Cout,
                       int M, int Nn, int lda, int ldb, int Ldc, int NallocB,
                       const float* __restrict__ segp, const int* __restrict__ posv,
                       const int* __restrict__ batchv, float* __restrict__ dseq) {
    constexpr int U   = KP / 8;
    constexpr int STR = (U + 1) * 16;
    constexpr int NK  = KP / 32;
    __shared__ __align__(16) char lds[64 * STR];

    const int tid  = threadIdx.x;
    const int lid  = tid & 63;
    const int wave = tid >> 6;
    const int wc   = wave * 64;
    const int bm   = blockIdx.x * 64;

    #pragma unroll
    for (int s = tid; s < 64 * U; s += 256) {
        int row = s / U, u = s - row * U;
        int ra = bm + row; if (ra >= M) ra = M - 1;
        *(uint4*)(&lds[row * STR + u * 16]) =
            *(const uint4*)(A + (size_t)ra * lda + u * 8);
    }
    __syncthreads();

    const int ku  = lid >> 4;
    const int rlo = lid & 15;
    const char* aBase = &lds[rlo * STR + ku * 16];

    u16* Cb = (u16*)Cout;

    const int nchunks = (NallocB + 255) >> 8;
    for (int nc = 0; nc < nchunks; ++nc) {
        const int bn = nc * 256 + wc;
        if (bn >= NallocB) continue;

        const u16* bp[4];
        #pragma unroll
        for (int j = 0; j < 4; ++j) {
            int br = bn + j * 16 + rlo;
            if (br > NallocB - 1) br = NallocB - 1;
            bp[j] = BT + (size_t)br * ldb + ku * 8;
        }

        f32x4 acc[4][4];
        #pragma unroll
        for (int i = 0; i < 4; ++i)
            #pragma unroll
            for (int j = 0; j < 4; ++j)
                acc[i][j] = (f32x4){0.0f, 0.0f, 0.0f, 0.0f};

        bf16x8 b0[4], b1[4];
        #pragma unroll
        for (int j = 0; j < 4; ++j) b0[j] = *(const bf16x8*)(bp[j]);
        if (NK > 1) {
            #pragma unroll
            for (int j = 0; j < 4; ++j) b1[j] = *(const bf16x8*)(bp[j] + 32);
        }

        #pragma unroll
        for (int t = 0; t < NK; ++t) {
            bf16x8 a[4];
            #pragma unroll
            for (int i = 0; i < 4; ++i)
                a[i] = *(const bf16x8*)(aBase + i * 16 * STR + t * 64);
            bf16x8 b2[4];
            if (t + 2 < NK) {
                #pragma unroll
                for (int j = 0; j < 4; ++j)
                    b2[j] = *(const bf16x8*)(bp[j] + (t + 2) * 32);
            }
            #pragma unroll
            for (int i = 0; i < 4; ++i)
                #pragma unroll
                for (int j = 0; j < 4; ++j)
                    acc[i][j] = __builtin_amdgcn_mfma_f32_16x16x32_bf16(a[i], b0[j], acc[i][j], 0, 0, 0);
            #pragma unroll
            for (int j = 0; j < 4; ++j) { b0[j] = b1[j]; b1[j] = b2[j]; }
        }

        const int nlim = (MODE == 7) ? Ldc : Nn;
        #pragma unroll
        for (int i = 0; i < 4; ++i) {
            #pragma unroll
            for (int r = 0; r < 4; ++r) {
                int m = bm + i * 16 + ku * 4 + r;
                if (m >= M) continue;
                size_t drow = 0;
                if (MODE == 7)
                    drow = ((size_t)posv[m] * BB + batchv[m]) * (size_t)HH;
                #pragma unroll
                for (int j = 0; j < 4; ++j) {
                    int n = bn + j * 16 + rlo;
                    if (n >= nlim) continue;
                    float v = acc[i][j][r];
                    if (MODE == 2)      Cb[(size_t)m * Ldc + n] = f2bf(fmaxf(v + bias[n], 0.0f));
                    else if (MODE == 7) {
                        float h = fmaxf(v + bias[n], 0.0f);
                        float d = h + segp[n];
                        Cb[(size_t)m * Ldc + n] = f2bf(d);
                        if (n < Nn) dseq[drow + n] = d;
                    }
                }
            }
        }
    }
}

template<int MODE, int KP>
static void pgemm(hipStream_t s, const u16* A, const u16* BT, const float* bias,
                  void* C, int M, int Nn, int lda, int ldb, int Ldc, int NallocB,
                  const float* segp = nullptr, const int* posv = nullptr,
                  const int* batchv = nullptr, float* dseq = nullptr) {
    panel_gemm_kernel<MODE, KP><<<cdiv(M, 64), 256, 0, s>>>(
        A, BT, bias, C, M, Nn, lda, ldb, Ldc, NallocB, segp, posv, batchv, dseq);
}

// ---------------------------------------------------------------------------
// MEGA-KERNEL bodies (device functions sharing one 75776-B smem arena)
// ---------------------------------------------------------------------------
__device__ void muvar_body(int blk, char* smem,
                           const u16* __restrict__ a0, const u16* __restrict__ mv1T,
                           const float* __restrict__ b768p,
                           const u16* __restrict__ mW2T, const u16* __restrict__ vW2T,
                           const float* __restrict__ mb2, const float* __restrict__ vb2,
                           u16* __restrict__ mu_b, u16* __restrict__ zlv_b, int M) {
    constexpr int UA = 48, STRA = (UA + 1) * 16;
    constexpr int STRT = 25 * 16;
    char* Alds = smem;                 // 50176 B
    char* Tlds = smem + 64 * STRA;     // 25600 B

    const int tid  = threadIdx.x;
    const int lid  = tid & 63;
    const int wave = tid >> 6;
    const int bm   = blk * 64;
    const int ku   = lid >> 4;
    const int rlo  = lid & 15;

    for (int s = tid; s < 64 * UA; s += 384) {
        int row = s / UA, u = s - row * UA;
        int ra = bm + row; if (ra >= M) ra = M - 1;
        *(uint4*)(&Alds[row * STRA + u * 16]) =
            *(const uint4*)(a0 + (size_t)ra * 384 + u * 8);
    }
    __syncthreads();

    const char* aBase1 = &Alds[rlo * STRA + ku * 16];
    const char* aBase2 = &Tlds[rlo * STRT + ku * 16];

    #pragma unroll 1
    for (int part = 0; part < 2; ++part) {
        const u16* B2 = part ? vW2T : mW2T;
        f32x4 acc2[4][4];
        #pragma unroll
        for (int i = 0; i < 4; ++i)
            #pragma unroll
            for (int j = 0; j < 4; ++j)
                acc2[i][j] = (f32x4){0.0f, 0.0f, 0.0f, 0.0f};

        #pragma unroll 1
        for (int h = 0; h < 2; ++h) {
            const u16* bp1[2];
            #pragma unroll
            for (int j = 0; j < 2; ++j) {
                int br = part * 384 + h * 192 + wave * 32 + j * 16 + rlo;
                bp1[j] = mv1T + (size_t)br * 384 + ku * 8;
            }
            f32x4 acc1[4][2];
            #pragma unroll
            for (int i = 0; i < 4; ++i)
                #pragma unroll
                for (int j = 0; j < 2; ++j)
                    acc1[i][j] = (f32x4){0.0f, 0.0f, 0.0f, 0.0f};

            bf16x8 c0[2], c1[2];
            #pragma unroll
            for (int j = 0; j < 2; ++j) c0[j] = *(const bf16x8*)(bp1[j]);
            #pragma unroll
            for (int j = 0; j < 2; ++j) c1[j] = *(const bf16x8*)(bp1[j] + 32);

            #pragma unroll
            for (int t = 0; t < 12; ++t) {
                bf16x8 a[4];
                #pragma unroll
                for (int i = 0; i < 4; ++i)
                    a[i] = *(const bf16x8*)(aBase1 + i * 16 * STRA + t * 64);
                bf16x8 c2[2];
                if (t + 2 < 12) {
                    #pragma unroll
                    for (int j = 0; j < 2; ++j)
                        c2[j] = *(const bf16x8*)(bp1[j] + (t + 2) * 32);
                }
                #pragma unroll
                for (int i = 0; i < 4; ++i)
                    #pragma unroll
                    for (int j = 0; j < 2; ++j)
                        acc1[i][j] = __builtin_amdgcn_mfma_f32_16x16x32_bf16(a[i], c0[j], acc1[i][j], 0, 0, 0);
                #pragma unroll
                for (int j = 0; j < 2; ++j) { c0[j] = c1[j]; c1[j] = c2[j]; }
            }

            #pragma unroll
            for (int i = 0; i < 4; ++i) {
                #pragma unroll
                for (int r = 0; r < 4; ++r) {
                    int m = i * 16 + ku * 4 + r;
                    #pragma unroll
                    for (int j = 0; j < 2; ++j) {
                        int n = wave * 32 + j * 16 + rlo;
                        float v = fmaxf(acc1[i][j][r] + b768p[part * 384 + h * 192 + n], 0.0f);
                        *(u16*)(&Tlds[m * STRT + n * 2]) = f2bf(v);
                    }
                }
            }
            __syncthreads();

            const u16* bp2[4];
            #pragma unroll
            for (int j = 0; j < 4; ++j) {
                int br = wave * 64 + j * 16 + rlo;
                if (br > 383) br = 383;
                bp2[j] = B2 + (size_t)br * 384 + h * 192 + ku * 8;
            }
            bf16x8 d0[4], d1[4];
            #pragma unroll
            for (int j = 0; j < 4; ++j) d0[j] = *(const bf16x8*)(bp2[j]);
            #pragma unroll
            for (int j = 0; j < 4; ++j) d1[j] = *(const bf16x8*)(bp2[j] + 32);

            #pragma unroll
            for (int t = 0; t < 6; ++t) {
                bf16x8 a[4];
                #pragma unroll
                for (int i = 0; i < 4; ++i)
                    a[i] = *(const bf16x8*)(aBase2 + i * 16 * STRT + t * 64);
                bf16x8 d2[4];
                if (t + 2 < 6) {
                    #pragma unroll
                    for (int j = 0; j < 4; ++j)
                        d2[j] = *(const bf16x8*)(bp2[j] + (t + 2) * 32);
                }
                #pragma unroll
                for (int i = 0; i < 4; ++i)
                    #pragma unroll
                    for (int j = 0; j < 4; ++j)
                        acc2[i][j] = __builtin_amdgcn_mfma_f32_16x16x32_bf16(a[i], d0[j], acc2[i][j], 0, 0, 0);
                #pragma unroll
                for (int j = 0; j < 4; ++j) { d0[j] = d1[j]; d1[j] = d2[j]; }
            }
            __syncthreads();
        }

        u16* outp = part ? zlv_b : mu_b;
        const float* bias2 = part ? vb2 : mb2;
        #pragma unroll
        for (int i = 0; i < 4; ++i) {
            #pragma unroll
            for (int r = 0; r < 4; ++r) {
                int gm = bm + i * 16 + ku * 4 + r;
                if (gm >= M) continue;
                #pragma unroll
                for (int j = 0; j < 4; ++j) {
                    int n = wave * 64 + j * 16 + rlo;
                    if (n >= 376) continue;
                    float v = acc2[i][j][r] + bias2[n];
                    if (part) v = -fabsf(v);
                    outp[(size_t)gm * 376 + n] = f2bf(v);
                }
            }
        }
    }
}

__device__ __forceinline__ int lds_swz(int row, int u) {
    return u ^ (row & 3) ^ ((row >> 2) & 3);
}

// con split-K GEMM body (atomicAdd into con_emb); waves 4-5 idle but barrier
__device__ void con_body(int rbid, char* smem,
                         const u16* __restrict__ A, const u16* __restrict__ BT,
                         float* __restrict__ Cf, int Kchunk) {
    uint4* As = (uint4*)smem;             // [2][512] = 16 KB
    uint4* Bs = (uint4*)(smem + 16384);   // 16 KB
    const int M = BB, Nn = 376, KA = 10272, lda = 10272, ldb = 10272,
              Ldc = 376, NallocB = 384;
    int bx = rbid % 3, rem = rbid / 3;
    int by = rem & 15, bz = rem >> 4;
    const int bn = bx * 128, bm = by * 128;
    const int k0 = bz * Kchunk;
    const int k1 = min(KA, k0 + Kchunk);
    const int nt = (k1 - k0) >> 5;

    const int tid = threadIdx.x;
    const bool act = tid < 256;
    const int lid = tid & 63;
    const int wave = (tid >> 6) & 3;
    const int wr = (wave >> 1) * 64, wc = (wave & 1) * 64;

    int wb[2];
    const u16* gA[2];
    const u16* gB[2];
    uint4 sa[2], sb[2];
    if (act) {
        #pragma unroll
        for (int it = 0; it < 2; ++it) {
            int s = tid + it * 256;
            int row = s >> 2, u = s & 3;
            wb[it] = row * 4 + lds_swz(row, u);
            int ra = bm + row; ra = ra < M ? ra : M - 1;
            int rb = bn + row; rb = rb < NallocB ? rb : NallocB - 1;
            gA[it] = A + (size_t)ra * lda + u * 8;
            gB[it] = BT + (size_t)rb * ldb + u * 8;
        }
        #pragma unroll
        for (int it = 0; it < 2; ++it) {
            sa[it] = *(const uint4*)(gA[it] + k0);
            sb[it] = *(const uint4*)(gB[it] + k0);
        }
        As[wb[0]] = sa[0]; As[wb[1]] = sa[1];
        Bs[wb[0]] = sb[0]; Bs[wb[1]] = sb[1];
        if (nt > 1) {
            #pragma unroll
            for (int it = 0; it < 2; ++it) {
                sa[it] = *(const uint4*)(gA[it] + k0 + 32);
                sb[it] = *(const uint4*)(gB[it] + k0 + 32);
            }
        }
    }

    f32x4 acc[4][4];
    #pragma unroll
    for (int i = 0; i < 4; ++i)
        #pragma unroll
        for (int j = 0; j < 4; ++j)
            acc[i][j] = (f32x4){0.0f, 0.0f, 0.0f, 0.0f};

    const int ku = lid >> 4;
    const int rlo = lid & 15;

    for (int t = 0; t < nt; ++t) {
        __syncthreads();
        const int cur = t & 1;
        if (act) {
            if (t + 1 < nt) {
                const int nxt = cur ^ 1;
                As[nxt * 512 + wb[0]] = sa[0]; As[nxt * 512 + wb[1]] = sa[1];
                Bs[nxt * 512 + wb[0]] = sb[0]; Bs[nxt * 512 + wb[1]] = sb[1];
            }
            bf16x8 aF[4], bF[4];
            #pragma unroll
            for (int i = 0; i < 4; ++i) {
                int row = wr + i * 16 + rlo;
                aF[i] = *(const bf16x8*)&As[cur * 512 + row * 4 + lds_swz(row, ku)];
            }
            #pragma unroll
            for (int j = 0; j < 4; ++j) {
                int row = wc + j * 16 + rlo;
                bF[j] = *(const bf16x8*)&Bs[cur * 512 + row * 4 + lds_swz(row, ku)];
            }
            if (t + 2 < nt) {
                int kk = k0 + (t + 2) * 32;
                #pragma unroll
                for (int it = 0; it < 2; ++it) {
                    sa[it] = *(const uint4*)(gA[it] + kk);
                    sb[it] = *(const uint4*)(gB[it] + kk);
                }
            }
            #pragma unroll
            for (int i = 0; i < 4; ++i)
                #pragma unroll
                for (int j = 0; j < 4; ++j)
                    acc[i][j] = __builtin_amdgcn_mfma_f32_16x16x32_bf16(aF[i], bF[j], acc[i][j], 0, 0, 0);
        }
    }

    if (act) {
        const int rq = lid >> 4;
        #pragma unroll
        for (int i = 0; i < 4; ++i) {
            #pragma unroll
            for (int r = 0; r < 4; ++r) {
                int m = bm + wr + i * 16 + rq * 4 + r;
                if (m >= M) continue;
                #pragma unroll
                for (int j = 0; j < 4; ++j) {
                    int n = bn + wc + j * 16 + rlo;
                    if (n < Nn) atomicAdd(&Cf[(size_t)m * Ldc + n], acc[i][j][r]);
                }
            }
        }
    }
}

__device__ void pool_body(int b, const u16* __restrict__ a0b,
                          const float* __restrict__ segp,
                          const int* __restrict__ goff, const int* __restrict__ nn,
                          u16* __restrict__ x2b) {
    int f = threadIdx.x;
    float m = 0.0f;
    if (f < HH) {
        int off2 = goff[b], sz = nn[b];
        float mx = -1e30f;
        for (int l = 0; l < sz; ++l)
            mx = fmaxf(mx, bf2f(a0b[(size_t)(off2 + l) * 384 + f]));
        m = mx - segp[f];
    }
    if (f < 384) x2b[(size_t)b * 384 + f] = f2bf(m);
}

__device__ void dseqpad_body(int rbid, const float* __restrict__ seg,
                             const int* __restrict__ nn, float4* __restrict__ out,
                             float* __restrict__ out_mask) {
    for (int idx = rbid * 384 + threadIdx.x; idx < LL * BB * 94; idx += 1024 * 384) {
        int k4 = idx % 94;
        int rowi = idx / 94;
        int b = rowi & (BB - 1);
        int l = rowi >> 11;
        if (l < nn[b]) continue;
        float4 s4 = ((const float4*)seg)[k4];
        float4 o; o.x = PADV + s4.x; o.y = PADV + s4.y; o.z = PADV + s4.z; o.w = PADV + s4.w;
        out[idx] = o;
    }
    for (int idx = rbid * 384 + threadIdx.x; idx < BB * LL; idx += 1024 * 384) {
        int b = idx / LL, l = idx % LL;
        out_mask[idx] = (l >= nn[b]) ? 1.0f : 0.0f;
    }
}

__device__ void padvec_body(char* smem, const float* __restrict__ seg,
                            const float* __restrict__ mW1, const float* __restrict__ mb1,
                            const float* __restrict__ mW2, const float* __restrict__ mb2,
                            const float* __restrict__ vW1, const float* __restrict__ vb1,
                            const float* __restrict__ vW2, const float* __restrict__ vb2,
                            float* __restrict__ mu_pad, float* __restrict__ zlv_pad,
                            double* kl_acc, int n_pad_rows) {
    float* t1 = (float*)smem;
    float* t2 = t1 + HH;
    float* red = t2 + HH;
    int j = threadIdx.x;
    if (j < HH) {
        float s1 = mb1[j], s2 = vb1[j];
        for (int k = 0; k < HH; ++k) {
            float pv = PADV + seg[k];
            s1 += pv * mW1[k * HH + j];
            s2 += pv * vW1[k * HH + j];
        }
        t1[j] = fmaxf(s1, 0.0f);
        t2[j] = fmaxf(s2, 0.0f);
    }
    __syncthreads();
    if (j < HH) {
        float m = mb2[j], v = vb2[j];
        for (int k = 0; k < HH; ++k) {
            m += t1[k] * mW2[k * HH + j];
            v += t2[k] * vW2[k * HH + j];
        }
        float z = -fabsf(v);
        mu_pad[j] = m;
        zlv_pad[j] = z;
        red[j] = 1.0f + z - m * m - expf(z);
    }
    __syncthreads();
    if (j == 0) {
        double s = 0.0;
        for (int k = 0; k < HH; ++k) s += (double)red[k];
        atomicAdd(kl_acc, s * (double)n_pad_rows);
    }
}

// mega: interleaved muvar + {con, pool, dseqpad+mask, padvec}
__global__ __launch_bounds__(384)
void mega_kernel(int MB,
                 const u16* a0b, const u16* mv1T, const float* b768p,
                 const u16* mW2T, const u16* vW2T, const float* mb2, const float* vb2,
                 u16* mu_b, u16* zlv_b, int N,
                 const u16* conb, const u16* condWT, float* con_emb, int conKchunk,
                 const float* segp, const int* goff, const int* nn, u16* x2b,
                 const float* seg, float* out_dseq, float* out_mask,
                 const float* mW1, const float* mb1, const float* vW1, const float* vb1,
                 const float* mW2f, const float* vW2f,
                 float* mu_pad, float* zlv_pad, double* kl_acc, int n_pad_rows) {
    __shared__ __align__(16) char smem[75776];
    int bid = blockIdx.x;
    int role, rbid;
    if (bid < 2 * MB) { role = bid & 1; rbid = bid >> 1; }
    else { role = 0; rbid = bid - MB; }

    if (role == 1) {
        muvar_body(rbid, smem, a0b, mv1T, b768p, mW2T, vW2T, mb2, vb2, mu_b, zlv_b, N);
    } else {
        if (rbid < 768) {
            con_body(rbid, smem, conb, condWT, con_emb, conKchunk);
        } else if (rbid < 768 + 2048) {
            pool_body(rbid - 768, a0b, segp, goff, nn, x2b);
        } else if (rbid < 768 + 2048 + 1024) {
            dseqpad_body(rbid - 768 - 2048, seg, nn, (float4*)out_dseq, out_mask);
        } else {
            padvec_body(smem, seg, mW1, mb1, mW2f, mb2, vW1, vb1, vW2f, vb2,
                        mu_pad, zlv_pad, kl_acc, n_pad_rows);
        }
    }
}

// ---------------------------------------------------------------------------
// classic tiled MFMA GEMM (fc1 / fc2)
// MODE: 2 bf16 relu(v+bias) pad-zeroed, 3 f32 atomicAdd
// ---------------------------------------------------------------------------
template<int MODE>
__global__ __launch_bounds__(256)
void mfma_gemm_kernel(const u16* __restrict__ A, const u16* __restrict__ BT,
                      const float* __restrict__ bias, void* __restrict__ Cout,
                      int M, int Nn, int KA, int lda, int ldb, int Ldc,
                      int NallocB, int Kchunk) {
    __shared__ uint4 As[2][512];
    __shared__ uint4 Bs[2][512];

    const int tid  = threadIdx.x;
    const int lid  = tid & 63;
    const int wave = tid >> 6;
    const int wr   = (wave >> 1) * 64;
    const int wc   = (wave & 1) * 64;
    const int bn   = blockIdx.x * 128;
    const int bm   = blockIdx.y * 128;
    const int k0   = blockIdx.z * Kchunk;
    const int k1   = min(KA, k0 + Kchunk);
    const int nt   = (k1 - k0) >> 5;

    int wb[2];
    const u16* gA[2];
    const u16* gB[2];
    #pragma unroll
    for (int it = 0; it < 2; ++it) {
        int s = tid + it * 256;
        int row = s >> 2, u = s & 3;
        wb[it] = row * 4 + lds_swz(row, u);
        int ra = bm + row; ra = ra < M ? ra : M - 1;
        int rb = bn + row; rb = rb < NallocB ? rb : NallocB - 1;
        gA[it] = A  + (size_t)ra * lda + u * 8;
        gB[it] = BT + (size_t)rb * ldb + u * 8;
    }

    f32x4 acc[4][4];
    #pragma unroll
    for (int i = 0; i < 4; ++i)
        #pragma unroll
        for (int j = 0; j < 4; ++j)
            acc[i][j] = (f32x4){0.0f, 0.0f, 0.0f, 0.0f};

    uint4 sa[2], sb[2];
    #pragma unroll
    for (int it = 0; it < 2; ++it) {
        sa[it] = *(const uint4*)(gA[it] + k0);
        sb[it] = *(const uint4*)(gB[it] + k0);
    }
    As[0][wb[0]] = sa[0]; As[0][wb[1]] = sa[1];
    Bs[0][wb[0]] = sb[0]; Bs[0][wb[1]] = sb[1];
    if (nt > 1) {
        #pragma unroll
        for (int it = 0; it < 2; ++it) {
            sa[it] = *(const uint4*)(gA[it] + k0 + 32);
            sb[it] = *(const uint4*)(gB[it] + k0 + 32);
        }
    }

    const int ku  = lid >> 4;
    const int rlo = lid & 15;

    for (int t = 0; t < nt; ++t) {
        __syncthreads();
        const int cur = t & 1;
        if (t + 1 < nt) {
            const int nxt = cur ^ 1;
            As[nxt][wb[0]] = sa[0]; As[nxt][wb[1]] = sa[1];
            Bs[nxt][wb[0]] = sb[0]; Bs[nxt][wb[1]] = sb[1];
        }
        bf16x8 aF[4], bF[4];
        #pragma unroll
        for (int i = 0; i < 4; ++i) {
            int row = wr + i * 16 + rlo;
            aF[i] = *(const bf16x8*)&As[cur][row * 4 + lds_swz(row, ku)];
        }
        #pragma unroll
        for (int j = 0; j < 4; ++j) {
            int row = wc + j * 16 + rlo;
            bF[j] = *(const bf16x8*)&Bs[cur][row * 4 + lds_swz(row, ku)];
        }
        if (t + 2 < nt) {
            int kk = k0 + (t + 2) * 32;
            #pragma unroll
            for (int it = 0; it < 2; ++it) {
                sa[it] = *(const uint4*)(gA[it] + kk);
                sb[it] = *(const uint4*)(gB[it] + kk);
            }
        }
        #pragma unroll
        for (int i = 0; i < 4; ++i)
            #pragma unroll
            for (int j = 0; j < 4; ++j)
                acc[i][j] = __builtin_amdgcn_mfma_f32_16x16x32_bf16(aF[i], bF[j], acc[i][j], 0, 0, 0);
    }

    float* Cf = (float*)Cout;
    u16*   Cb = (u16*)Cout;
    const int rq = lid >> 4;
    #pragma unroll
    for (int i = 0; i < 4; ++i) {
        #pragma unroll
        for (int r = 0; r < 4; ++r) {
            int m = bm + wr + i * 16 + rq * 4 + r;
            if (m >= M) continue;
            #pragma unroll
            for (int j = 0; j < 4; ++j) {
                int n = bn + wc + j * 16 + rlo;
                float v = acc[i][j][r];
                if (MODE == 3) {
                    if (n < Nn) atomicAdd(&Cf[(size_t)m * Ldc + n], v);
                } else if (MODE == 2) {
                    if (n < Ldc) {
                        float o = 0.0f;
                        if (n < Nn) o = fmaxf(v + (bias ? bias[n] : 0.0f), 0.0f);
                        Cb[(size_t)m * Ldc + n] = f2bf(o);
                    }
                }
            }
        }
    }
}

template<int MODE>
static void mgemm(hipStream_t s, const u16* A, const u16* BT, const float* bias,
                  void* C, int M, int Nn, int KA, int lda, int ldb, int Ldc,
                  int NallocB, int splitk) {
    int ncols = (MODE == 2) ? Ldc : Nn;
    dim3 grid(cdiv(ncols, 128), cdiv(M, 128), splitk);
    int Kchunk = (cdiv(KA, splitk) + 31) & ~31;
    mfma_gemm_kernel<MODE><<<grid, 256, 0, s>>>(A, BT, bias, C, M, Nn, KA, lda, ldb,
                                                Ldc, NallocB, Kchunk);
}

// ---------------------------------------------------------------------------
// fused amvo + kl(real rows); mu/zlv bf16 compact [N][376]
// ---------------------------------------------------------------------------
__global__ __launch_bounds__(256)
void amvo_kl4_kernel(const u16x4* __restrict__ mu, const u16x4* __restrict__ zlv,
                     const float* __restrict__ mu_pad, const float* __restrict__ zlv_pad,
                     const float* __restrict__ con_emb, const float* __restrict__ aff,
                     const float4* __restrict__ eps4,
                     const int* __restrict__ nn, const int* __restrict__ goff,
                     float4* __restrict__ out, float* __restrict__ kl_part) {
    const int T4 = LL * BB * 94;
    float kls = 0.0f;
    for (int idx = blockIdx.x * 256 + threadIdx.x; idx < T4; idx += 2048 * 256) {
        int k4 = idx % 94;
        int rowi = idx / 94;
        int b = rowi & (BB - 1);
        int l = rowi >> 11;
        float4 m, z;
        if (l < nn[b]) {
            size_t o = (size_t)(goff[b] + l) * 94 + k4;
            u16x4 mm = mu[o], zz = zlv[o];
            m.x = bf2f(mm.x); m.y = bf2f(mm.y); m.z = bf2f(mm.z); m.w = bf2f(mm.w);
            z.x = bf2f(zz.x); z.y = bf2f(zz.y); z.z = bf2f(zz.z); z.w = bf2f(zz.w);
            kls += (1.0f + z.x - m.x * m.x - __expf(z.x))
                 + (1.0f + z.y - m.y * m.y - __expf(z.y))
                 + (1.0f + z.z - m.z * m.z - __expf(z.z))
                 + (1.0f + z.w - m.w * m.w - __expf(z.w));
        } else {
            m = ((const float4*)mu_pad)[k4];
            z = ((const float4*)zlv_pad)[k4];
        }
        float4 e = eps4[idx];
        float4 c = ((const float4*)con_emb)[(size_t)b * 94 + k4];
        float af = aff[b];
        float4 o;
        o.x = m.x + __expf(0.5f * z.x) * e.x + c.x + af;
        o.y = m.y + __expf(0.5f * z.y) * e.y + c.y + af;
        o.z = m.z + __expf(0.5f * z.z) * e.z + c.z + af;
        o.w = m.w + __expf(0.5f * z.w) * e.w + c.w + af;
        out[idx] = o;
    }
    __shared__ float red[256];
    red[threadIdx.x] = kls;
    __syncthreads();
    for (int s = 128; s > 0; s >>= 1) {
        if (threadIdx.x < s) red[threadIdx.x] += red[threadIdx.x + s];
        __syncthreads();
    }
    if (threadIdx.x == 0) kl_part[blockIdx.x] = red[0];
}

__global__ __launch_bounds__(256)
void kl_final_kernel(const float* __restrict__ kl_part, int nparts,
                     const double* __restrict__ kl_acc, float* __restrict__ out) {
    __shared__ double red[256];
    double s = 0.0;
    for (int i = threadIdx.x; i < nparts; i += 256) s += (double)kl_part[i];
    red[threadIdx.x] = s;
    __syncthreads();
    for (int st = 128; st > 0; st >>= 1) {
        if (threadIdx.x < st) red[threadIdx.x] += red[threadIdx.x + st];
        __syncthreads();
    }
    if (threadIdx.x == 0) out[0] = (float)(-0.5 * (red[0] + *kl_acc) / 64.0);
}

// ---------------------------------------------------------------------------
extern "C" void kernel_launch(void* const* d_in, const int* in_sizes, int n_in,
                              void* d_out, int out_size, void* d_ws, size_t ws_size,
                              hipStream_t stream) {
    const float* x      = (const float*)d_in[0];
    const float* con    = (const float*)d_in[1];
    const float* aff    = (const float*)d_in[2];
    const float* eps    = (const float*)d_in[3];
    const int*   eidx   = (const int*)  d_in[4];
    const int*   batch  = (const int*)  d_in[5];
    const int*   nn     = (const int*)  d_in[6];
    const int*   pos    = (const int*)  d_in[7];
    const float* seg    = (const float*)d_in[8];
    const float* W1     = (const float*)d_in[9];
    const float* b1     = (const float*)d_in[10];
    const float* W2     = (const float*)d_in[11];
    const float* b2     = (const float*)d_in[12];
    const float* W3     = (const float*)d_in[13];
    const float* b3     = (const float*)d_in[14];
    const float* condW  = (const float*)d_in[15];
    const float* condB  = (const float*)d_in[16];
    const float* mW1    = (const float*)d_in[17];
    const float* mb1    = (const float*)d_in[18];
    const float* mW2    = (const float*)d_in[19];
    const float* mb2    = (const float*)d_in[20];
    const float* vW1    = (const float*)d_in[21];
    const float* vb1    = (const float*)d_in[22];
    const float* vW2    = (const float*)d_in[23];
    const float* vb2    = (const float*)d_in[24];
    const float* fc1W   = (const float*)d_in[25];
    const float* fc1b   = (const float*)d_in[26];
    const float* fc2W   = (const float*)d_in[27];
    const float* fc2b   = (const float*)d_in[28];

    const int N = in_sizes[0] / DF_;          // 81725
    const int E = in_sizes[4] / 2;            // 326900
    const int* erow = eidx;
    const int* ecol = eidx + E;
    const int n_pad_rows = LL * BB - N;

    const size_t dseqN = (size_t)LL * BB * HH;
    float* out_dseq = (float*)d_out;
    float* out_amvo = out_dseq + dseqN;
    float* out_mask = out_amvo + dseqN;
    float* out_pmvo = out_mask + (size_t)BB * LL;
    float* out_kl   = out_pmvo + (size_t)BB * FIN;

    // ---- workspace carve ----
    char* p = (char*)d_ws;
    size_t off = 0;
    auto alloc = [&](size_t bytes) -> char* {
        char* q = p + off;
        off = (off + bytes + 255) & ~(size_t)255;
        return q;
    };
    float*  dinv    = (float*) alloc((size_t)N * 4);
    int*    deg     = (int*)   alloc((size_t)N * 4);
    int*    rowptr  = (int*)   alloc((size_t)(N + 1) * 4);
    int*    cursor  = (int*)   alloc((size_t)N * 4);
    int*    csr_src = (int*)   alloc((size_t)E * 4);
    int*    bsum    = (int*)   alloc((size_t)128 * 4);
    int*    goff    = (int*)   alloc((size_t)(BB + 1) * 4);
    float*  mu_pad  = (float*) alloc(HH * 4);
    float*  zlv_pad = (float*) alloc(HH * 4);
    double* kl_acc  = (double*)alloc(8);
    float*  kl_part = (float*) alloc(2048 * 4);
    float*  b1p     = (float*) alloc(192 * 4);
    float*  b2p     = (float*) alloc(288 * 4);
    float*  b3p     = (float*) alloc(384 * 4);
    float*  segp    = (float*) alloc(384 * 4);
    float*  b768p   = (float*) alloc(768 * 4);
    float*  con_emb = (float*) alloc((size_t)BB * HH * 4);
    u16*    x2b     = (u16*)   alloc((size_t)BB * 384 * 2);
    u16*    tfcb    = (u16*)   alloc((size_t)BB * 1024 * 2);
    u16*    W1T     = (u16*)   alloc((size_t)192 * 96 * 2);
    u16*    W2T     = (u16*)   alloc((size_t)288 * 192 * 2);
    u16*    W3T     = (u16*)   alloc((size_t)384 * 288 * 2);
    u16*    mv1T    = (u16*)   alloc((size_t)768 * 384 * 2);   // [mW1T;vW1T]
    u16*    mW2T    = (u16*)   alloc((size_t)384 * 384 * 2);
    u16*    vW2T    = (u16*)   alloc((size_t)384 * 384 * 2);
    u16*    condWT  = (u16*)   alloc((size_t)384 * 10272 * 2);
    u16*    fc1WT   = (u16*)   alloc((size_t)1024 * 384 * 2);
    u16*    fc2WT   = (u16*)   alloc((size_t)256 * 1024 * 2);
    u16*    a0b     = (u16*)   alloc((size_t)N * 384 * 2);     // bf16(h3+seg) padded
    u16*    mu_b    = (u16*)   alloc((size_t)N * 376 * 2);
    u16*    zlv_b   = (u16*)   alloc((size_t)N * 376 * 2);
    u16*    aggb    = (u16*)   alloc((size_t)N * 288 * 2);
    u16*    actb    = (u16*)   alloc((size_t)N * 288 * 2);

    // bf16 scratch in the (not-yet-written) amvo output region
    char* q = (char*)out_amvo;
    size_t qoff = 0;
    auto qalloc = [&](size_t bytes) -> char* {
        char* r = q + qoff;
        qoff = (qoff + bytes + 255) & ~(size_t)255;
        return r;
    };
    u16* conb = (u16*)qalloc((size_t)BB * 10272 * 2);   // 42 MB
    (void)ws_size; (void)n_in; (void)out_size;

    // ---- degree / dinv / CSR / goff ----
    const int NB = cdiv(N, 1024);
    zero_int_kernel<<<cdiv(N, 256), 256, 0, stream>>>(deg, N);
    count_deg_kernel<<<cdiv(E, 256), 256, 0, stream>>>(ecol, deg, E);
    dinv_kernel<<<cdiv(N, 256), 256, 0, stream>>>(deg, dinv, N);
    scan1_kernel<<<NB, 1024, 0, stream>>>(deg, N, rowptr, bsum);
    scan2_kernel<<<1, 64, 0, stream>>>(bsum, NB, rowptr, N);
    scan3_kernel<<<NB, 1024, 0, stream>>>(rowptr, cursor, bsum, N);
    fill_csr_kernel<<<cdiv(E, 256), 256, 0, stream>>>(erow, ecol, cursor, csr_src, E);
    goff_kernel<<<1, 1024, 0, stream>>>(nn, goff, kl_acc);

    // ---- padded bias / seg vectors ----
    pads_kernel<<<8, 256, 0, stream>>>(b1, b2, b3, seg, mb1, vb1,
                                       b1p, b2p, b3p, segp, b768p);

    // ---- batched weight transposes ----
    {
        TJobs J; J.njobs = NJOBS;
        const float* Ws[NJOBS] = {W1, W2, W3, mW1, vW1, mW2, vW2, condW, fc1W, fc2W};
        u16* Os[NJOBS] = {W1T, W2T, W3T, mv1T, mv1T + 384 * 384, mW2T, vW2T,
                          condWT, fc1WT, fc2WT};
        int Ks[NJOBS]  = {94, 188, 282, 376, 376, 376, 376, 10272, 376, 1024};
        int Ns[NJOBS]  = {188, 282, 376, 376, 376, 376, 376, 376, 1024, 256};
        int Kp[NJOBS]  = {96, 192, 288, 384, 384, 384, 384, 10272, 384, 1024};
        int Np[NJOBS]  = {192, 288, 384, 384, 384, 384, 384, 384, 1024, 256};
        int base = 0;
        for (int i = 0; i < NJOBS; ++i) {
            J.W[i] = Ws[i]; J.out[i] = Os[i]; J.K[i] = Ks[i]; J.Nn[i] = Ns[i];
            J.ktiles[i] = Kp[i] / 32;
            J.base[i] = base;
            base += (Kp[i] / 32) * (Np[i] / 32);
        }
        transpose_batch_kernel<<<base, 256, 0, stream>>>(J);
    }

    cast4_kernel<<<cdiv(BB * 10272 / 4, 256), 256, 0, stream>>>(
        (const float4*)con, (u16x4*)conb, BB * 10272 / 4);

    // ---- GCN layer 1 (aggregate-first) ----
    agg_kernel<12, 16, true><<<cdiv(N, 16), 256, 0, stream>>>(
        x, rowptr, csr_src, dinv, aggb, N);
    pgemm<2, 96>(stream, aggb, W1T, b1p, actb, N, 192, 96, 96, 192, 192);

    // ---- GCN layer 2 ----
    agg_kernel<24, 32, false><<<cdiv(N, 8), 256, 0, stream>>>(
        actb, rowptr, csr_src, dinv, aggb, N);
    pgemm<2, 192>(stream, aggb, W2T, b2p, actb, N, 288, 192, 192, 288, 288);

    // ---- GCN layer 3: agg -> gemm with fused a0b/dseq epilogue ----
    agg_kernel<36, 64, false><<<cdiv(N, 4), 256, 0, stream>>>(
        actb, rowptr, csr_src, dinv, aggb, N);
    pgemm<7, 288>(stream, aggb, W3T, b3p, a0b, N, 376, 288, 288, 384, 384,
                  segp, pos, batch, out_dseq);

    // ---- init con_emb with bias (con atomics land on top, inside mega) ----
    init_bias_kernel<<<cdiv(BB * HH, 256), 256, 0, stream>>>(con_emb, condB, (size_t)BB * HH, HH);

    // ---- MEGA: muvar interleaved with con / pool / dseq-pad+mask / pad_vec ----
    {
        const int MB = cdiv(N, 64);               // 1277 muvar blocks
        const int XB = 768 + 2048 + 1024 + 1;     // misc blocks
        const int conKchunk = (cdiv(10272, 16) + 31) & ~31;   // 672
        mega_kernel<<<MB + XB, 384, 0, stream>>>(
            MB, a0b, mv1T, b768p, mW2T, vW2T, mb2, vb2, mu_b, zlv_b, N,
            conb, condWT, con_emb, conKchunk,
            segp, goff, nn, x2b,
            seg, out_dseq, out_mask,
            mW1, mb1, vW1, vb1, mW2, vW2,
            mu_pad, zlv_pad, kl_acc, n_pad_rows);
    }

    // ---- amvo + kl ----
    amvo_kl4_kernel<<<2048, 256, 0, stream>>>((const u16x4*)mu_b, (const u16x4*)zlv_b,
                                              mu_pad, zlv_pad, con_emb, aff,
                                              (const float4*)eps, nn, goff,
                                              (float4*)out_amvo, kl_part);
    kl_final_kernel<<<1, 256, 0, stream>>>(kl_part, 2048, kl_acc, out_kl);

    // ---- pmvo head ----
    mgemm<2>(stream, x2b, fc1WT, fc1b, tfcb, BB, 1024, 384, 384, 384, 1024, 1024, 1);
    init_bias_kernel<<<cdiv(BB * FIN, 256), 256, 0, stream>>>(out_pmvo, fc2b, (size_t)BB * FIN, FIN);
    mgemm<3>(stream, tfcb, fc2WT, nullptr, out_pmvo, BB, 256, 1024, 1024, 1024, 256, 256, 8);
}

// Round 16
// 1218.993 us; speedup vs baseline: 1.1484x; 1.1484x over previous
//
#include <hip/hip_runtime.h>
#include <hip/hip_bf16.h>
#include <math.h>

typedef unsigned short u16;
typedef __attribute__((ext_vector_type(8))) short bf16x8;
typedef __attribute__((ext_vector_type(4))) float f32x4;
struct __align__(8) u16x4 { u16 x, y, z, w; };

constexpr int BB   = 2048;
constexpr int DF_  = 94;
constexpr int HH   = 376;
constexpr int LL   = 64;
constexpr int FIN  = 256;
constexpr float PADV = -999.0f;

static inline int cdiv(int a, int b) { return (a + b - 1) / b; }

__device__ __forceinline__ u16 f2bf(float v) {
    union { float f; unsigned u; } c; c.f = v;
    unsigned r = c.u + 0x7FFF + ((c.u >> 16) & 1);   // RNE
    return (u16)(r >> 16);
}
__device__ __forceinline__ float bf2f(u16 v) {
    union { unsigned u; float f; } c; c.u = ((unsigned)v) << 16;
    return c.f;
}
__device__ __forceinline__ void unpack8(uint4 v, float* t) {
    union { unsigned u; float f; } c;
    c.u = v.x << 16;          t[0] = c.f;
    c.u = v.x & 0xFFFF0000u;  t[1] = c.f;
    c.u = v.y << 16;          t[2] = c.f;
    c.u = v.y & 0xFFFF0000u;  t[3] = c.f;
    c.u = v.z << 16;          t[4] = c.f;
    c.u = v.z & 0xFFFF0000u;  t[5] = c.f;
    c.u = v.w << 16;          t[6] = c.f;
    c.u = v.w & 0xFFFF0000u;  t[7] = c.f;
}

// ---------------------------------------------------------------------------
// degree / CSR build
// ---------------------------------------------------------------------------
__global__ __launch_bounds__(256)
void zero_int_kernel(int* a, int n) {
    int i = blockIdx.x * 256 + threadIdx.x;
    if (i < n) a[i] = 0;
}

__global__ __launch_bounds__(256)
void count_deg_kernel(const int* __restrict__ col, int* deg, int E) {
    int e = blockIdx.x * 256 + threadIdx.x;
    if (e < E) atomicAdd(&deg[col[e]], 1);
}

__global__ __launch_bounds__(256)
void dinv_kernel(const int* __restrict__ deg, float* dinv, int N) {
    int i = blockIdx.x * 256 + threadIdx.x;
    if (i < N) dinv[i] = rsqrtf((float)(1 + deg[i]));
}

__global__ __launch_bounds__(1024)
void scan1_kernel(const int* __restrict__ deg, int N, int* __restrict__ rowptr,
                  int* __restrict__ bsum) {
    __shared__ int sh[1024];
    int t = threadIdx.x, base = blockIdx.x * 1024;
    int v = (base + t < N) ? deg[base + t] : 0;
    sh[t] = v; __syncthreads();
    for (int o = 1; o < 1024; o <<= 1) {
        int x = (t >= o) ? sh[t - o] : 0;
        __syncthreads();
        sh[t] += x;
        __syncthreads();
    }
    if (base + t < N) rowptr[base + t] = sh[t] - v;
    if (t == 1023) bsum[blockIdx.x] = sh[1023];
}

__global__ void scan2_kernel(int* bsum, int nb, int* rowptr, int N) {
    if (threadIdx.x == 0) {
        int s = 0;
        for (int i = 0; i < nb; ++i) { int v = bsum[i]; bsum[i] = s; s += v; }
        rowptr[N] = s;
    }
}

__global__ __launch_bounds__(1024)
void scan3_kernel(int* __restrict__ rowptr, int* __restrict__ cursor,
                  const int* __restrict__ bsum, int N) {
    int i = blockIdx.x * 1024 + threadIdx.x;
    if (i < N) {
        int v = rowptr[i] + bsum[blockIdx.x];
        rowptr[i] = v;
        cursor[i] = v;
    }
}

__global__ __launch_bounds__(256)
void fill_csr_kernel(const int* __restrict__ row, const int* __restrict__ col,
                     int* __restrict__ cursor, int* __restrict__ csr_src, int E) {
    int e = blockIdx.x * 256 + threadIdx.x;
    if (e < E) {
        int pos = atomicAdd(&cursor[col[e]], 1);
        csr_src[pos] = row[e];
    }
}

__global__ __launch_bounds__(1024)
void goff_kernel(const int* __restrict__ nn, int* __restrict__ goff, double* kl_acc) {
    __shared__ int sh[1024];
    __shared__ int carry;
    int t = threadIdx.x;
    if (t == 0) carry = 0;
    __syncthreads();
    for (int base = 0; base < BB; base += 1024) {
        int v = nn[base + t];
        sh[t] = v; __syncthreads();
        for (int o = 1; o < 1024; o <<= 1) {
            int x = (t >= o) ? sh[t - o] : 0;
            __syncthreads();
            sh[t] += x;
            __syncthreads();
        }
        goff[base + t] = carry + sh[t] - v;
        int tot = sh[1023];
        __syncthreads();
        if (t == 0) carry += tot;
        __syncthreads();
    }
    if (t == 0) { goff[BB] = carry; *kl_acc = 0.0; }
}

// ---------------------------------------------------------------------------
// merged pad-vector prep
// ---------------------------------------------------------------------------
__global__ __launch_bounds__(256)
void pads_kernel(const float* b1, const float* b2, const float* b3,
                 const float* seg, const float* mb1, const float* vb1,
                 float* b1p, float* b2p, float* b3p, float* segp, float* b768p) {
    int i = blockIdx.x * 256 + threadIdx.x;
    if (i < 192)            b1p[i] = (i < 188) ? b1[i] : 0.0f;
    else if (i < 480)  { int j = i - 192;  b2p[j]   = (j < 282) ? b2[j]  : 0.0f; }
    else if (i < 864)  { int j = i - 480;  b3p[j]   = (j < 376) ? b3[j]  : 0.0f; }
    else if (i < 1248) { int j = i - 864;  segp[j]  = (j < 376) ? seg[j] : 0.0f; }
    else if (i < 1632) { int j = i - 1248; b768p[j] = (j < 376) ? mb1[j] : 0.0f; }
    else if (i < 2016) { int j = i - 1632; b768p[384 + j] = (j < 376) ? vb1[j] : 0.0f; }
}

__global__ __launch_bounds__(256)
void init_bias_kernel(float* __restrict__ out, const float* __restrict__ bias,
                      size_t total, int F) {
    size_t idx = (size_t)blockIdx.x * 256 + threadIdx.x;
    if (idx < total) out[idx] = bias[idx % F];
}

__global__ __launch_bounds__(256)
void cast4_kernel(const float4* __restrict__ in, u16x4* __restrict__ out, int total4) {
    int idx = blockIdx.x * 256 + threadIdx.x;
    if (idx >= total4) return;
    float4 v = in[idx];
    u16x4 o; o.x = f2bf(v.x); o.y = f2bf(v.y); o.z = f2bf(v.z); o.w = f2bf(v.w);
    out[idx] = o;
}

// ---------------------------------------------------------------------------
// batched weight transpose+cast
// ---------------------------------------------------------------------------
constexpr int NJOBS = 10;
struct TJobs {
    const float* W[NJOBS];
    u16* out[NJOBS];
    int K[NJOBS], Nn[NJOBS], base[NJOBS], ktiles[NJOBS];
    int njobs;
};

__global__ __launch_bounds__(256)
void transpose_batch_kernel(TJobs jobs) {
    __shared__ float t[32][33];
    int tb = blockIdx.x;
    int j = 0;
    #pragma unroll
    for (int i = 1; i < NJOBS; ++i)
        if (i < jobs.njobs && tb >= jobs.base[i]) j = i;
    int rel = tb - jobs.base[j];
    int gk = (rel % jobs.ktiles[j]) * 32;
    int gn = (rel / jobs.ktiles[j]) * 32;
    const float* W = jobs.W[j];
    u16* out = jobs.out[j];
    int K = jobs.K[j], Nn = jobs.Nn[j];
    int Kpad = jobs.ktiles[j] * 32;

    int tx = threadIdx.x & 31, ty = threadIdx.x >> 5;
    #pragma unroll
    for (int r = 0; r < 4; ++r) {
        int row = gk + ty + r * 8, col = gn + tx;
        t[ty + r * 8][tx] = (row < K && col < Nn) ? W[(size_t)row * Nn + col] : 0.0f;
    }
    __syncthreads();
    #pragma unroll
    for (int r = 0; r < 4; ++r) {
        int n = gn + ty + r * 8, k = gk + tx;
        out[(size_t)n * Kpad + k] = f2bf(t[tx][ty + r * 8]);
    }
}

// ---------------------------------------------------------------------------
// aggregate-first GCN sparse step
// ---------------------------------------------------------------------------
template<int U, int G, bool F32IN>
__global__ __launch_bounds__(256)
void agg_kernel(const void* __restrict__ inp, const int* __restrict__ rowptr,
                const int* __restrict__ csr_src, const float* __restrict__ dinv,
                u16* __restrict__ out, int N) {
    constexpr int NPB = 256 / G;
    int u = threadIdx.x & (G - 1);
    int n = blockIdx.x * NPB + threadIdx.x / G;
    if (n >= N || u >= U) return;
    float di = dinv[n];
    float acc[8];
    if (F32IN) {
        const float* xr = (const float*)inp + (size_t)n * 94 + u * 8;
        #pragma unroll
        for (int j = 0; j < 8; ++j)
            acc[j] = (u * 8 + j < 94) ? di * xr[j] : 0.0f;
    } else {
        float t[8];
        unpack8(((const uint4*)inp)[(size_t)n * U + u], t);
        #pragma unroll
        for (int j = 0; j < 8; ++j) acc[j] = di * t[j];
    }
    int e0 = rowptr[n], e1 = rowptr[n + 1];
    for (int e = e0; e < e1; ++e) {
        int r = csr_src[e];
        float w = dinv[r];
        if (F32IN) {
            const float* rr = (const float*)inp + (size_t)r * 94 + u * 8;
            #pragma unroll
            for (int j = 0; j < 8; ++j)
                if (u * 8 + j < 94) acc[j] = fmaf(w, rr[j], acc[j]);
        } else {
            float t[8];
            unpack8(((const uint4*)inp)[(size_t)r * U + u], t);
            #pragma unroll
            for (int j = 0; j < 8; ++j) acc[j] = fmaf(w, t[j], acc[j]);
        }
    }
    unsigned w0 = (unsigned)f2bf(di * acc[0]) | ((unsigned)f2bf(di * acc[1]) << 16);
    unsigned w1 = (unsigned)f2bf(di * acc[2]) | ((unsigned)f2bf(di * acc[3]) << 16);
    unsigned w2 = (unsigned)f2bf(di * acc[4]) | ((unsigned)f2bf(di * acc[5]) << 16);
    unsigned w3 = (unsigned)f2bf(di * acc[6]) | ((unsigned)f2bf(di * acc[7]) << 16);
    ((uint4*)out)[(size_t)n * U + u] = make_uint4(w0, w1, w2, w3);
}

// ---------------------------------------------------------------------------
// A-panel-resident GEMM (layer GEMMs)
// MODE: 2 bf16 relu(v+bias), 7 L3 epilogue (a0b + dseq scatter)
// ---------------------------------------------------------------------------
template<int MODE, int KP>
__global__ __launch_bounds__(256)
void panel_gemm_kernel(const u16* __restrict__ A, const u16* __restrict__ BT,
                       const float* __restrict__ bias, void* __restrict__ Cout,
                       int M, int Nn, int lda, int ldb, int Ldc, int NallocB,
                       const float* __restrict__ segp, const int* __restrict__ posv,
                       const int* __restrict__ batchv, float* __restrict__ dseq) {
    constexpr int U   = KP / 8;
    constexpr int STR = (U + 1) * 16;
    constexpr int NK  = KP / 32;
    __shared__ __align__(16) char lds[64 * STR];

    const int tid  = threadIdx.x;
    const int lid  = tid & 63;
    const int wave = tid >> 6;
    const int wc   = wave * 64;
    const int bm   = blockIdx.x * 64;

    #pragma unroll
    for (int s = tid; s < 64 * U; s += 256) {
        int row = s / U, u = s - row * U;
        int ra = bm + row; if (ra >= M) ra = M - 1;
        *(uint4*)(&lds[row * STR + u * 16]) =
            *(const uint4*)(A + (size_t)ra * lda + u * 8);
    }
    __syncthreads();

    const int ku  = lid >> 4;
    const int rlo = lid & 15;
    const char* aBase = &lds[rlo * STR + ku * 16];

    u16* Cb = (u16*)Cout;

    const int nchunks = (NallocB + 255) >> 8;
    for (int nc = 0; nc < nchunks; ++nc) {
        const int bn = nc * 256 + wc;
        if (bn >= NallocB) continue;

        const u16* bp[4];
        #pragma unroll
        for (int j = 0; j < 4; ++j) {
            int br = bn + j * 16 + rlo;
            if (br > NallocB - 1) br = NallocB - 1;
            bp[j] = BT + (size_t)br * ldb + ku * 8;
        }

        f32x4 acc[4][4];
        #pragma unroll
        for (int i = 0; i < 4; ++i)
            #pragma unroll
            for (int j = 0; j < 4; ++j)
                acc[i][j] = (f32x4){0.0f, 0.0f, 0.0f, 0.0f};

        bf16x8 b0[4], b1[4];
        #pragma unroll
        for (int j = 0; j < 4; ++j) b0[j] = *(const bf16x8*)(bp[j]);
        if (NK > 1) {
            #pragma unroll
            for (int j = 0; j < 4; ++j) b1[j] = *(const bf16x8*)(bp[j] + 32);
        }

        #pragma unroll
        for (int t = 0; t < NK; ++t) {
            bf16x8 a[4];
            #pragma unroll
            for (int i = 0; i < 4; ++i)
                a[i] = *(const bf16x8*)(aBase + i * 16 * STR + t * 64);
            bf16x8 b2[4];
            if (t + 2 < NK) {
                #pragma unroll
                for (int j = 0; j < 4; ++j)
                    b2[j] = *(const bf16x8*)(bp[j] + (t + 2) * 32);
            }
            #pragma unroll
            for (int i = 0; i < 4; ++i)
                #pragma unroll
                for (int j = 0; j < 4; ++j)
                    acc[i][j] = __builtin_amdgcn_mfma_f32_16x16x32_bf16(a[i], b0[j], acc[i][j], 0, 0, 0);
            #pragma unroll
            for (int j = 0; j < 4; ++j) { b0[j] = b1[j]; b1[j] = b2[j]; }
        }

        const int nlim = (MODE == 7) ? Ldc : Nn;
        #pragma unroll
        for (int i = 0; i < 4; ++i) {
            #pragma unroll
            for (int r = 0; r < 4; ++r) {
                int m = bm + i * 16 + ku * 4 + r;
                if (m >= M) continue;
                size_t drow = 0;
                if (MODE == 7)
                    drow = ((size_t)posv[m] * BB + batchv[m]) * (size_t)HH;
                #pragma unroll
                for (int j = 0; j < 4; ++j) {
                    int n = bn + j * 16 + rlo;
                    if (n >= nlim) continue;
                    float v = acc[i][j][r];
                    if (MODE == 2)      Cb[(size_t)m * Ldc + n] = f2bf(fmaxf(v + bias[n], 0.0f));
                    else if (MODE == 7) {
                        float h = fmaxf(v + bias[n], 0.0f);
                        float d = h + segp[n];
                        Cb[(size_t)m * Ldc + n] = f2bf(d);
                        if (n < Nn) dseq[drow + n] = d;
                    }
                }
            }
        }
    }
}

template<int MODE, int KP>
static void pgemm(hipStream_t s, const u16* A, const u16* BT, const float* bias,
                  void* C, int M, int Nn, int lda, int ldb, int Ldc, int NallocB,
                  const float* segp = nullptr, const int* posv = nullptr,
                  const int* batchv = nullptr, float* dseq = nullptr) {
    panel_gemm_kernel<MODE, KP><<<cdiv(M, 64), 256, 0, s>>>(
        A, BT, bias, C, M, Nn, lda, ldb, Ldc, NallocB, segp, posv, batchv, dseq);
}

// ---------------------------------------------------------------------------
// FUSED mu/logvar chain (round-8 structure + 4-deep B prefetch;
// part/h outer loops not unrolled)
// ---------------------------------------------------------------------------
__global__ __launch_bounds__(384)
void muvar_kernel(const u16* __restrict__ a0, const u16* __restrict__ mv1T,
                  const float* __restrict__ b768p,
                  const u16* __restrict__ mW2T, const u16* __restrict__ vW2T,
                  const float* __restrict__ mb2, const float* __restrict__ vb2,
                  u16* __restrict__ mu_b, u16* __restrict__ zlv_b, int M) {
    constexpr int UA = 48, STRA = (UA + 1) * 16;   // a0 row stride 784 B
    constexpr int STRT = 25 * 16;                  // t1 row stride 400 B
    __shared__ __align__(16) char Alds[64 * STRA]; // 50176 B
    __shared__ __align__(16) char Tlds[64 * STRT]; // 25600 B

    const int tid  = threadIdx.x;
    const int lid  = tid & 63;
    const int wave = tid >> 6;          // 0..5
    const int bm   = blockIdx.x * 64;
    const int ku   = lid >> 4;
    const int rlo  = lid & 15;

    for (int s = tid; s < 64 * UA; s += 384) {
        int row = s / UA, u = s - row * UA;
        int ra = bm + row; if (ra >= M) ra = M - 1;
        *(uint4*)(&Alds[row * STRA + u * 16]) =
            *(const uint4*)(a0 + (size_t)ra * 384 + u * 8);
    }
    __syncthreads();

    const char* aBase1 = &Alds[rlo * STRA + ku * 16];
    const char* aBase2 = &Tlds[rlo * STRT + ku * 16];

    #pragma unroll 1
    for (int part = 0; part < 2; ++part) {
        const u16* B2 = part ? vW2T : mW2T;
        f32x4 acc2[4][4];
        #pragma unroll
        for (int i = 0; i < 4; ++i)
            #pragma unroll
            for (int j = 0; j < 4; ++j)
                acc2[i][j] = (f32x4){0.0f, 0.0f, 0.0f, 0.0f};

        #pragma unroll 1
        for (int h = 0; h < 2; ++h) {
            // ---- GEMM1: t1half = relu(a0 @ W1cols + bias), wave owns 32 cols
            const u16* bp1[2];
            #pragma unroll
            for (int j = 0; j < 2; ++j) {
                int br = part * 384 + h * 192 + wave * 32 + j * 16 + rlo;
                bp1[j] = mv1T + (size_t)br * 384 + ku * 8;
            }
            f32x4 acc1[4][2];
            #pragma unroll
            for (int i = 0; i < 4; ++i)
                #pragma unroll
                for (int j = 0; j < 2; ++j)
                    acc1[i][j] = (f32x4){0.0f, 0.0f, 0.0f, 0.0f};

            // 4-deep rotating B queue
            bf16x8 cq[4][2];
            #pragma unroll
            for (int d = 0; d < 4; ++d)
                #pragma unroll
                for (int j = 0; j < 2; ++j)
                    cq[d][j] = *(const bf16x8*)(bp1[j] + d * 32);

            #pragma unroll
            for (int t = 0; t < 12; ++t) {
                bf16x8 a[4];
                #pragma unroll
                for (int i = 0; i < 4; ++i)
                    a[i] = *(const bf16x8*)(aBase1 + i * 16 * STRA + t * 64);
                bf16x8 cur[2];
                #pragma unroll
                for (int j = 0; j < 2; ++j) cur[j] = cq[t & 3][j];
                if (t + 4 < 12) {
                    #pragma unroll
                    for (int j = 0; j < 2; ++j)
                        cq[t & 3][j] = *(const bf16x8*)(bp1[j] + (t + 4) * 32);
                }
                #pragma unroll
                for (int i = 0; i < 4; ++i)
                    #pragma unroll
                    for (int j = 0; j < 2; ++j)
                        acc1[i][j] = __builtin_amdgcn_mfma_f32_16x16x32_bf16(a[i], cur[j], acc1[i][j], 0, 0, 0);
            }

            // write t1half (relu + bias) into Tlds as bf16 rows [64][192]
            #pragma unroll
            for (int i = 0; i < 4; ++i) {
                #pragma unroll
                for (int r = 0; r < 4; ++r) {
                    int m = i * 16 + ku * 4 + r;
                    #pragma unroll
                    for (int j = 0; j < 2; ++j) {
                        int n = wave * 32 + j * 16 + rlo;
                        float v = fmaxf(acc1[i][j][r] + b768p[part * 384 + h * 192 + n], 0.0f);
                        *(u16*)(&Tlds[m * STRT + n * 2]) = f2bf(v);
                    }
                }
            }
            __syncthreads();

            // ---- GEMM2 partial: acc2 += t1half @ W2[:, h*192:...], wave owns 64 cols
            const u16* bp2[4];
            #pragma unroll
            for (int j = 0; j < 4; ++j) {
                int br = wave * 64 + j * 16 + rlo;
                if (br > 383) br = 383;
                bp2[j] = B2 + (size_t)br * 384 + h * 192 + ku * 8;
            }
            bf16x8 dq[4][4];
            #pragma unroll
            for (int d = 0; d < 4; ++d)
                #pragma unroll
                for (int j = 0; j < 4; ++j)
                    dq[d][j] = *(const bf16x8*)(bp2[j] + d * 32);

            #pragma unroll
            for (int t = 0; t < 6; ++t) {
                bf16x8 a[4];
                #pragma unroll
                for (int i = 0; i < 4; ++i)
                    a[i] = *(const bf16x8*)(aBase2 + i * 16 * STRT + t * 64);
                bf16x8 cur[4];
                #pragma unroll
                for (int j = 0; j < 4; ++j) cur[j] = dq[t & 3][j];
                if (t + 4 < 6) {
                    #pragma unroll
                    for (int j = 0; j < 4; ++j)
                        dq[t & 3][j] = *(const bf16x8*)(bp2[j] + (t + 4) * 32);
                }
                #pragma unroll
                for (int i = 0; i < 4; ++i)
                    #pragma unroll
                    for (int j = 0; j < 4; ++j)
                        acc2[i][j] = __builtin_amdgcn_mfma_f32_16x16x32_bf16(a[i], cur[j], acc2[i][j], 0, 0, 0);
            }
            __syncthreads();   // before next half overwrites Tlds
        }

        // ---- epilogue: write mu (part 0) / zlv (part 1), bf16 compact [N][376]
        u16* outp = part ? zlv_b : mu_b;
        const float* bias2 = part ? vb2 : mb2;
        #pragma unroll
        for (int i = 0; i < 4; ++i) {
            #pragma unroll
            for (int r = 0; r < 4; ++r) {
                int gm = bm + i * 16 + ku * 4 + r;
                if (gm >= M) continue;
                #pragma unroll
                for (int j = 0; j < 4; ++j) {
                    int n = wave * 64 + j * 16 + rlo;
                    if (n >= 376) continue;
                    float v = acc2[i][j][r] + bias2[n];
                    if (part) v = -fabsf(v);
                    outp[(size_t)gm * 376 + n] = f2bf(v);
                }
            }
        }
    }
}

// ---------------------------------------------------------------------------
// classic tiled MFMA GEMM (con / fc1 / fc2)
// MODE: 2 bf16 relu(v+bias) pad-zeroed, 3 f32 atomicAdd
// ---------------------------------------------------------------------------
__device__ __forceinline__ int lds_swz(int row, int u) {
    return u ^ (row & 3) ^ ((row >> 2) & 3);
}

template<int MODE>
__global__ __launch_bounds__(256)
void mfma_gemm_kernel(const u16* __restrict__ A, const u16* __restrict__ BT,
                      const float* __restrict__ bias, void* __restrict__ Cout,
                      int M, int Nn, int KA, int lda, int ldb, int Ldc,
                      int NallocB, int Kchunk) {
    __shared__ uint4 As[2][512];
    __shared__ uint4 Bs[2][512];

    const int tid  = threadIdx.x;
    const int lid  = tid & 63;
    const int wave = tid >> 6;
    const int wr   = (wave >> 1) * 64;
    const int wc   = (wave & 1) * 64;
    const int bn   = blockIdx.x * 128;
    const int bm   = blockIdx.y * 128;
    const int k0   = blockIdx.z * Kchunk;
    const int k1   = min(KA, k0 + Kchunk);
    const int nt   = (k1 - k0) >> 5;

    int wb[2];
    const u16* gA[2];
    const u16* gB[2];
    #pragma unroll
    for (int it = 0; it < 2; ++it) {
        int s = tid + it * 256;
        int row = s >> 2, u = s & 3;
        wb[it] = row * 4 + lds_swz(row, u);
        int ra = bm + row; ra = ra < M ? ra : M - 1;
        int rb = bn + row; rb = rb < NallocB ? rb : NallocB - 1;
        gA[it] = A  + (size_t)ra * lda + u * 8;
        gB[it] = BT + (size_t)rb * ldb + u * 8;
    }

    f32x4 acc[4][4];
    #pragma unroll
    for (int i = 0; i < 4; ++i)
        #pragma unroll
        for (int j = 0; j < 4; ++j)
            acc[i][j] = (f32x4){0.0f, 0.0f, 0.0f, 0.0f};

    uint4 sa[2], sb[2];
    #pragma unroll
    for (int it = 0; it < 2; ++it) {
        sa[it] = *(const uint4*)(gA[it] + k0);
        sb[it] = *(const uint4*)(gB[it] + k0);
    }
    As[0][wb[0]] = sa[0]; As[0][wb[1]] = sa[1];
    Bs[0][wb[0]] = sb[0]; Bs[0][wb[1]] = sb[1];
    if (nt > 1) {
        #pragma unroll
        for (int it = 0; it < 2; ++it) {
            sa[it] = *(const uint4*)(gA[it] + k0 + 32);
            sb[it] = *(const uint4*)(gB[it] + k0 + 32);
        }
    }

    const int ku  = lid >> 4;
    const int rlo = lid & 15;

    for (int t = 0; t < nt; ++t) {
        __syncthreads();
        const int cur = t & 1;
        if (t + 1 < nt) {
            const int nxt = cur ^ 1;
            As[nxt][wb[0]] = sa[0]; As[nxt][wb[1]] = sa[1];
            Bs[nxt][wb[0]] = sb[0]; Bs[nxt][wb[1]] = sb[1];
        }
        bf16x8 aF[4], bF[4];
        #pragma unroll
        for (int i = 0; i < 4; ++i) {
            int row = wr + i * 16 + rlo;
            aF[i] = *(const bf16x8*)&As[cur][row * 4 + lds_swz(row, ku)];
        }
        #pragma unroll
        for (int j = 0; j < 4; ++j) {
            int row = wc + j * 16 + rlo;
            bF[j] = *(const bf16x8*)&Bs[cur][row * 4 + lds_swz(row, ku)];
        }
        if (t + 2 < nt) {
            int kk = k0 + (t + 2) * 32;
            #pragma unroll
            for (int it = 0; it < 2; ++it) {
                sa[it] = *(const uint4*)(gA[it] + kk);
                sb[it] = *(const uint4*)(gB[it] + kk);
            }
        }
        #pragma unroll
        for (int i = 0; i < 4; ++i)
            #pragma unroll
            for (int j = 0; j < 4; ++j)
                acc[i][j] = __builtin_amdgcn_mfma_f32_16x16x32_bf16(aF[i], bF[j], acc[i][j], 0, 0, 0);
    }

    float* Cf = (float*)Cout;
    u16*   Cb = (u16*)Cout;
    const int rq = lid >> 4;
    #pragma unroll
    for (int i = 0; i < 4; ++i) {
        #pragma unroll
        for (int r = 0; r < 4; ++r) {
            int m = bm + wr + i * 16 + rq * 4 + r;
            if (m >= M) continue;
            #pragma unroll
            for (int j = 0; j < 4; ++j) {
                int n = bn + wc + j * 16 + rlo;
                float v = acc[i][j][r];
                if (MODE == 3) {
                    if (n < Nn) atomicAdd(&Cf[(size_t)m * Ldc + n], v);
                } else if (MODE == 2) {
                    if (n < Ldc) {
                        float o = 0.0f;
                        if (n < Nn) o = fmaxf(v + (bias ? bias[n] : 0.0f), 0.0f);
                        Cb[(size_t)m * Ldc + n] = f2bf(o);
                    }
                }
            }
        }
    }
}

template<int MODE>
static void mgemm(hipStream_t s, const u16* A, const u16* BT, const float* bias,
                  void* C, int M, int Nn, int KA, int lda, int ldb, int Ldc,
                  int NallocB, int splitk) {
    int ncols = (MODE == 2) ? Ldc : Nn;
    dim3 grid(cdiv(ncols, 128), cdiv(M, 128), splitk);
    int Kchunk = (cdiv(KA, splitk) + 31) & ~31;
    mfma_gemm_kernel<MODE><<<grid, 256, 0, s>>>(A, BT, bias, C, M, Nn, KA, lda, ldb,
                                                Ldc, NallocB, Kchunk);
}

// ---------------------------------------------------------------------------
// pad rows of d_seq + mask (merged)
// ---------------------------------------------------------------------------
__global__ __launch_bounds__(256)
void dseq_pad_mask_kernel(const float* __restrict__ seg, const int* __restrict__ nn,
                          float4* __restrict__ out, float* __restrict__ out_mask) {
    int idx = blockIdx.x * 256 + threadIdx.x;
    if (idx < BB * LL) {
        int b = idx / LL, l = idx % LL;
        out_mask[idx] = (l >= nn[b]) ? 1.0f : 0.0f;
    }
    if (idx >= LL * BB * 94) return;
    int k4 = idx % 94;
    int rowi = idx / 94;
    int b = rowi & (BB - 1);
    int l = rowi >> 11;
    if (l < nn[b]) return;
    float4 s4 = ((const float4*)seg)[k4];
    float4 o; o.x = PADV + s4.x; o.y = PADV + s4.y; o.z = PADV + s4.z; o.w = PADV + s4.w;
    out[idx] = o;
}

// ---------------------------------------------------------------------------
// pad-row mu/zlv + exact pad kl contribution (fp32)
// ---------------------------------------------------------------------------
__global__ __launch_bounds__(384)
void pad_vec_kernel(const float* __restrict__ seg,
                    const float* __restrict__ mW1, const float* __restrict__ mb1,
                    const float* __restrict__ mW2, const float* __restrict__ mb2,
                    const float* __restrict__ vW1, const float* __restrict__ vb1,
                    const float* __restrict__ vW2, const float* __restrict__ vb2,
                    float* __restrict__ mu_pad, float* __restrict__ zlv_pad,
                    double* kl_acc, int n_pad_rows) {
    __shared__ float t1[HH], t2[HH], red[HH];
    int j = threadIdx.x;
    if (j < HH) {
        float s1 = mb1[j], s2 = vb1[j];
        for (int k = 0; k < HH; ++k) {
            float p = PADV + seg[k];
            s1 += p * mW1[k * HH + j];
            s2 += p * vW1[k * HH + j];
        }
        t1[j] = fmaxf(s1, 0.0f);
        t2[j] = fmaxf(s2, 0.0f);
    }
    __syncthreads();
    if (j < HH) {
        float m = mb2[j], v = vb2[j];
        for (int k = 0; k < HH; ++k) {
            m += t1[k] * mW2[k * HH + j];
            v += t2[k] * vW2[k * HH + j];
        }
        float z = -fabsf(v);
        mu_pad[j]  = m;
        zlv_pad[j] = z;
        red[j] = 1.0f + z - m * m - expf(z);
    }
    __syncthreads();
    if (j == 0) {
        double s = 0.0;
        for (int k = 0; k < HH; ++k) s += (double)red[k];
        atomicAdd(kl_acc, s * (double)n_pad_rows);
    }
}

// ---------------------------------------------------------------------------
// fused amvo + kl(real rows); mu/zlv bf16 compact [N][376]
// ---------------------------------------------------------------------------
__global__ __launch_bounds__(256)
void amvo_kl4_kernel(const u16x4* __restrict__ mu, const u16x4* __restrict__ zlv,
                     const float* __restrict__ mu_pad, const float* __restrict__ zlv_pad,
                     const float* __restrict__ con_emb, const float* __restrict__ aff,
                     const float4* __restrict__ eps4,
                     const int* __restrict__ nn, const int* __restrict__ goff,
                     float4* __restrict__ out, float* __restrict__ kl_part) {
    const int T4 = LL * BB * 94;
    float kls = 0.0f;
    for (int idx = blockIdx.x * 256 + threadIdx.x; idx < T4; idx += 2048 * 256) {
        int k4 = idx % 94;
        int rowi = idx / 94;
        int b = rowi & (BB - 1);
        int l = rowi >> 11;
        float4 m, z;
        if (l < nn[b]) {
            size_t o = (size_t)(goff[b] + l) * 94 + k4;
            u16x4 mm = mu[o], zz = zlv[o];
            m.x = bf2f(mm.x); m.y = bf2f(mm.y); m.z = bf2f(mm.z); m.w = bf2f(mm.w);
            z.x = bf2f(zz.x); z.y = bf2f(zz.y); z.z = bf2f(zz.z); z.w = bf2f(zz.w);
            kls += (1.0f + z.x - m.x * m.x - __expf(z.x))
                 + (1.0f + z.y - m.y * m.y - __expf(z.y))
                 + (1.0f + z.z - m.z * m.z - __expf(z.z))
                 + (1.0f + z.w - m.w * m.w - __expf(z.w));
        } else {
            m = ((const float4*)mu_pad)[k4];
            z = ((const float4*)zlv_pad)[k4];
        }
        float4 e = eps4[idx];
        float4 c = ((const float4*)con_emb)[(size_t)b * 94 + k4];
        float af = aff[b];
        float4 o;
        o.x = m.x + __expf(0.5f * z.x) * e.x + c.x + af;
        o.y = m.y + __expf(0.5f * z.y) * e.y + c.y + af;
        o.z = m.z + __expf(0.5f * z.z) * e.z + c.z + af;
        o.w = m.w + __expf(0.5f * z.w) * e.w + c.w + af;
        out[idx] = o;
    }
    __shared__ float red[256];
    red[threadIdx.x] = kls;
    __syncthreads();
    for (int s = 128; s > 0; s >>= 1) {
        if (threadIdx.x < s) red[threadIdx.x] += red[threadIdx.x + s];
        __syncthreads();
    }
    if (threadIdx.x == 0) kl_part[blockIdx.x] = red[0];
}

__global__ __launch_bounds__(256)
void kl_final_kernel(const float* __restrict__ kl_part, int nparts,
                     const double* __restrict__ kl_acc, float* __restrict__ out) {
    __shared__ double red[256];
    double s = 0.0;
    for (int i = threadIdx.x; i < nparts; i += 256) s += (double)kl_part[i];
    red[threadIdx.x] = s;
    __syncthreads();
    for (int st = 128; st > 0; st >>= 1) {
        if (threadIdx.x < st) red[threadIdx.x] += red[threadIdx.x + st];
        __syncthreads();
    }
    if (threadIdx.x == 0) out[0] = (float)(-0.5 * (red[0] + *kl_acc) / 64.0);
}

// ---------------------------------------------------------------------------
// global max pool from a0b (= bf16(h3+seg)): x2 = max(a0b) - seg
// ---------------------------------------------------------------------------
__global__ __launch_bounds__(384)
void pool_kernel(const u16* __restrict__ a0b, const float* __restrict__ segp,
                 const int* __restrict__ goff, const int* __restrict__ nn,
                 u16* __restrict__ x2b) {
    int b = blockIdx.x;
    int f = threadIdx.x;
    float m = 0.0f;
    if (f < HH) {
        int off = goff[b], sz = nn[b];
        float mx = -1e30f;
        for (int l = 0; l < sz; ++l)
            mx = fmaxf(mx, bf2f(a0b[(size_t)(off + l) * 384 + f]));
        m = mx - segp[f];
    }
    x2b[(size_t)b * 384 + f] = f2bf(m);
}

// ---------------------------------------------------------------------------
extern "C" void kernel_launch(void* const* d_in, const int* in_sizes, int n_in,
                              void* d_out, int out_size, void* d_ws, size_t ws_size,
                              hipStream_t stream) {
    const float* x      = (const float*)d_in[0];
    const float* con    = (const float*)d_in[1];
    const float* aff    = (const float*)d_in[2];
    const float* eps    = (const float*)d_in[3];
    const int*   eidx   = (const int*)  d_in[4];
    const int*   batch  = (const int*)  d_in[5];
    const int*   nn     = (const int*)  d_in[6];
    const int*   pos    = (const int*)  d_in[7];
    const float* seg    = (const float*)d_in[8];
    const float* W1     = (const float*)d_in[9];
    const float* b1     = (const float*)d_in[10];
    const float* W2     = (const float*)d_in[11];
    const float* b2     = (const float*)d_in[12];
    const float* W3     = (const float*)d_in[13];
    const float* b3     = (const float*)d_in[14];
    const float* condW  = (const float*)d_in[15];
    const float* condB  = (const float*)d_in[16];
    const float* mW1    = (const float*)d_in[17];
    const float* mb1    = (const float*)d_in[18];
    const float* mW2    = (const float*)d_in[19];
    const float* mb2    = (const float*)d_in[20];
    const float* vW1    = (const float*)d_in[21];
    const float* vb1    = (const float*)d_in[22];
    const float* vW2    = (const float*)d_in[23];
    const float* vb2    = (const float*)d_in[24];
    const float* fc1W   = (const float*)d_in[25];
    const float* fc1b   = (const float*)d_in[26];
    const float* fc2W   = (const float*)d_in[27];
    const float* fc2b   = (const float*)d_in[28];

    const int N = in_sizes[0] / DF_;          // 81725
    const int E = in_sizes[4] / 2;            // 326900
    const int* erow = eidx;
    const int* ecol = eidx + E;
    const int n_pad_rows = LL * BB - N;

    const size_t dseqN = (size_t)LL * BB * HH;
    float* out_dseq = (float*)d_out;
    float* out_amvo = out_dseq + dseqN;
    float* out_mask = out_amvo + dseqN;
    float* out_pmvo = out_mask + (size_t)BB * LL;
    float* out_kl   = out_pmvo + (size_t)BB * FIN;

    // ---- workspace carve ----
    char* p = (char*)d_ws;
    size_t off = 0;
    auto alloc = [&](size_t bytes) -> char* {
        char* q = p + off;
        off = (off + bytes + 255) & ~(size_t)255;
        return q;
    };
    float*  dinv    = (float*) alloc((size_t)N * 4);
    int*    deg     = (int*)   alloc((size_t)N * 4);
    int*    rowptr  = (int*)   alloc((size_t)(N + 1) * 4);
    int*    cursor  = (int*)   alloc((size_t)N * 4);
    int*    csr_src = (int*)   alloc((size_t)E * 4);
    int*    bsum    = (int*)   alloc((size_t)128 * 4);
    int*    goff    = (int*)   alloc((size_t)(BB + 1) * 4);
    float*  mu_pad  = (float*) alloc(HH * 4);
    float*  zlv_pad = (float*) alloc(HH * 4);
    double* kl_acc  = (double*)alloc(8);
    float*  kl_part = (float*) alloc(2048 * 4);
    float*  b1p     = (float*) alloc(192 * 4);
    float*  b2p     = (float*) alloc(288 * 4);
    float*  b3p     = (float*) alloc(384 * 4);
    float*  segp    = (float*) alloc(384 * 4);
    float*  b768p   = (float*) alloc(768 * 4);
    float*  con_emb = (float*) alloc((size_t)BB * HH * 4);
    u16*    x2b     = (u16*)   alloc((size_t)BB * 384 * 2);
    u16*    tfcb    = (u16*)   alloc((size_t)BB * 1024 * 2);
    u16*    W1T     = (u16*)   alloc((size_t)192 * 96 * 2);
    u16*    W2T     = (u16*)   alloc((size_t)288 * 192 * 2);
    u16*    W3T     = (u16*)   alloc((size_t)384 * 288 * 2);
    u16*    mv1T    = (u16*)   alloc((size_t)768 * 384 * 2);   // [mW1T;vW1T]
    u16*    mW2T    = (u16*)   alloc((size_t)384 * 384 * 2);
    u16*    vW2T    = (u16*)   alloc((size_t)384 * 384 * 2);
    u16*    condWT  = (u16*)   alloc((size_t)384 * 10272 * 2);
    u16*    fc1WT   = (u16*)   alloc((size_t)1024 * 384 * 2);
    u16*    fc2WT   = (u16*)   alloc((size_t)256 * 1024 * 2);
    u16*    a0b     = (u16*)   alloc((size_t)N * 384 * 2);     // bf16(h3+seg) padded
    u16*    mu_b    = (u16*)   alloc((size_t)N * 376 * 2);
    u16*    zlv_b   = (u16*)   alloc((size_t)N * 376 * 2);
    u16*    aggb    = (u16*)   alloc((size_t)N * 288 * 2);
    u16*    actb    = (u16*)   alloc((size_t)N * 288 * 2);

    // bf16 scratch in the (not-yet-written) amvo output region
    char* q = (char*)out_amvo;
    size_t qoff = 0;
    auto qalloc = [&](size_t bytes) -> char* {
        char* r = q + qoff;
        qoff = (qoff + bytes + 255) & ~(size_t)255;
        return r;
    };
    u16* conb = (u16*)qalloc((size_t)BB * 10272 * 2);   // 42 MB
    (void)ws_size; (void)n_in; (void)out_size;

    // ---- degree / dinv / CSR / goff ----
    const int NB = cdiv(N, 1024);
    zero_int_kernel<<<cdiv(N, 256), 256, 0, stream>>>(deg, N);
    count_deg_kernel<<<cdiv(E, 256), 256, 0, stream>>>(ecol, deg, E);
    dinv_kernel<<<cdiv(N, 256), 256, 0, stream>>>(deg, dinv, N);
    scan1_kernel<<<NB, 1024, 0, stream>>>(deg, N, rowptr, bsum);
    scan2_kernel<<<1, 64, 0, stream>>>(bsum, NB, rowptr, N);
    scan3_kernel<<<NB, 1024, 0, stream>>>(rowptr, cursor, bsum, N);
    fill_csr_kernel<<<cdiv(E, 256), 256, 0, stream>>>(erow, ecol, cursor, csr_src, E);
    goff_kernel<<<1, 1024, 0, stream>>>(nn, goff, kl_acc);

    // ---- padded bias / seg vectors ----
    pads_kernel<<<8, 256, 0, stream>>>(b1, b2, b3, seg, mb1, vb1,
                                       b1p, b2p, b3p, segp, b768p);

    // ---- batched weight transposes ----
    {
        TJobs J; J.njobs = NJOBS;
        const float* Ws[NJOBS] = {W1, W2, W3, mW1, vW1, mW2, vW2, condW, fc1W, fc2W};
        u16* Os[NJOBS] = {W1T, W2T, W3T, mv1T, mv1T + 384 * 384, mW2T, vW2T,
                          condWT, fc1WT, fc2WT};
        int Ks[NJOBS]  = {94, 188, 282, 376, 376, 376, 376, 10272, 376, 1024};
        int Ns[NJOBS]  = {188, 282, 376, 376, 376, 376, 376, 376, 1024, 256};
        int Kp[NJOBS]  = {96, 192, 288, 384, 384, 384, 384, 10272, 384, 1024};
        int Np[NJOBS]  = {192, 288, 384, 384, 384, 384, 384, 384, 1024, 256};
        int base = 0;
        for (int i = 0; i < NJOBS; ++i) {
            J.W[i] = Ws[i]; J.out[i] = Os[i]; J.K[i] = Ks[i]; J.Nn[i] = Ns[i];
            J.ktiles[i] = Kp[i] / 32;
            J.base[i] = base;
            base += (Kp[i] / 32) * (Np[i] / 32);
        }
        transpose_batch_kernel<<<base, 256, 0, stream>>>(J);
    }

    cast4_kernel<<<cdiv(BB * 10272 / 4, 256), 256, 0, stream>>>(
        (const float4*)con, (u16x4*)conb, BB * 10272 / 4);

    // ---- GCN layer 1 (aggregate-first) ----
    agg_kernel<12, 16, true><<<cdiv(N, 16), 256, 0, stream>>>(
        x, rowptr, csr_src, dinv, aggb, N);
    pgemm<2, 96>(stream, aggb, W1T, b1p, actb, N, 192, 96, 96, 192, 192);

    // ---- GCN layer 2 ----
    agg_kernel<24, 32, false><<<cdiv(N, 8), 256, 0, stream>>>(
        actb, rowptr, csr_src, dinv, aggb, N);
    pgemm<2, 192>(stream, aggb, W2T, b2p, actb, N, 288, 192, 192, 288, 288);

    // ---- GCN layer 3: agg -> gemm with fused a0b/dseq epilogue ----
    agg_kernel<36, 64, false><<<cdiv(N, 4), 256, 0, stream>>>(
        actb, rowptr, csr_src, dinv, aggb, N);
    pgemm<7, 288>(stream, aggb, W3T, b3p, a0b, N, 376, 288, 288, 384, 384,
                  segp, pos, batch, out_dseq);

    // ---- dseq pad rows + mask (merged) / pool ----
    dseq_pad_mask_kernel<<<cdiv(LL * BB * 94, 256), 256, 0, stream>>>(
        seg, nn, (float4*)out_dseq, out_mask);
    pool_kernel<<<BB, 384, 0, stream>>>(a0b, segp, goff, nn, x2b);

    // ---- FUSED mu/logvar chain (4-deep B prefetch) ----
    muvar_kernel<<<cdiv(N, 64), 384, 0, stream>>>(
        a0b, mv1T, b768p, mW2T, vW2T, mb2, vb2, mu_b, zlv_b, N);

    pad_vec_kernel<<<1, 384, 0, stream>>>(seg, mW1, mb1, mW2, mb2, vW1, vb1, vW2, vb2,
                                          mu_pad, zlv_pad, kl_acc, n_pad_rows);

    // ---- conditioning embedding ----
    init_bias_kernel<<<cdiv(BB * HH, 256), 256, 0, stream>>>(con_emb, condB, (size_t)BB * HH, HH);
    mgemm<3>(stream, conb, condWT, nullptr, con_emb, BB, 376, 10272, 10272, 10272, 376, 384, 16);

    // ---- amvo + kl ----
    amvo_kl4_kernel<<<2048, 256, 0, stream>>>((const u16x4*)mu_b, (const u16x4*)zlv_b,
                                              mu_pad, zlv_pad, con_emb, aff,
                                              (const float4*)eps, nn, goff,
                                              (float4*)out_amvo, kl_part);
    kl_final_kernel<<<1, 256, 0, stream>>>(kl_part, 2048, kl_acc, out_kl);

    // ---- pmvo head ----
    mgemm<2>(stream, x2b, fc1WT, fc1b, tfcb, BB, 1024, 384, 384, 384, 1024, 1024, 1);
    init_bias_kernel<<<cdiv(BB * FIN, 256), 256, 0, stream>>>(out_pmvo, fc2b, (size_t)BB * FIN, FIN);
    mgemm<3>(stream, tfcb, fc2WT, nullptr, out_pmvo, BB, 256, 1024, 1024, 1024, 256, 256, 8);
}

// Round 17
// 1209.320 us; speedup vs baseline: 1.1576x; 1.0080x over previous
//
#include <hip/hip_runtime.h>
#include <hip/hip_bf16.h>
#include <math.h>

typedef unsigned short u16;
typedef __attribute__((ext_vector_type(8))) short bf16x8;
typedef __attribute__((ext_vector_type(4))) float f32x4;
struct __align__(8) u16x4 { u16 x, y, z, w; };

constexpr int BB   = 2048;
constexpr int DF_  = 94;
constexpr int HH   = 376;
constexpr int LL   = 64;
constexpr int FIN  = 256;
constexpr float PADV = -999.0f;

static inline int cdiv(int a, int b) { return (a + b - 1) / b; }

__device__ __forceinline__ u16 f2bf(float v) {
    union { float f; unsigned u; } c; c.f = v;
    unsigned r = c.u + 0x7FFF + ((c.u >> 16) & 1);   // RNE
    return (u16)(r >> 16);
}
__device__ __forceinline__ float bf2f(u16 v) {
    union { unsigned u; float f; } c; c.u = ((unsigned)v) << 16;
    return c.f;
}
__device__ __forceinline__ void unpack8(uint4 v, float* t) {
    union { unsigned u; float f; } c;
    c.u = v.x << 16;          t[0] = c.f;
    c.u = v.x & 0xFFFF0000u;  t[1] = c.f;
    c.u = v.y << 16;          t[2] = c.f;
    c.u = v.y & 0xFFFF0000u;  t[3] = c.f;
    c.u = v.z << 16;          t[4] = c.f;
    c.u = v.z & 0xFFFF0000u;  t[5] = c.f;
    c.u = v.w << 16;          t[6] = c.f;
    c.u = v.w & 0xFFFF0000u;  t[7] = c.f;
}

// ---------------------------------------------------------------------------
// degree / CSR build
// ---------------------------------------------------------------------------
__global__ __launch_bounds__(256)
void zero_int_kernel(int* a, int n) {
    int i = blockIdx.x * 256 + threadIdx.x;
    if (i < n) a[i] = 0;
}

__global__ __launch_bounds__(256)
void count_deg_kernel(const int* __restrict__ col, int* deg, int E) {
    int e = blockIdx.x * 256 + threadIdx.x;
    if (e < E) atomicAdd(&deg[col[e]], 1);
}

__global__ __launch_bounds__(256)
void dinv_kernel(const int* __restrict__ deg, float* dinv, int N) {
    int i = blockIdx.x * 256 + threadIdx.x;
    if (i < N) dinv[i] = rsqrtf((float)(1 + deg[i]));
}

__global__ __launch_bounds__(1024)
void scan1_kernel(const int* __restrict__ deg, int N, int* __restrict__ rowptr,
                  int* __restrict__ bsum) {
    __shared__ int sh[1024];
    int t = threadIdx.x, base = blockIdx.x * 1024;
    int v = (base + t < N) ? deg[base + t] : 0;
    sh[t] = v; __syncthreads();
    for (int o = 1; o < 1024; o <<= 1) {
        int x = (t >= o) ? sh[t - o] : 0;
        __syncthreads();
        sh[t] += x;
        __syncthreads();
    }
    if (base + t < N) rowptr[base + t] = sh[t] - v;
    if (t == 1023) bsum[blockIdx.x] = sh[1023];
}

__global__ void scan2_kernel(int* bsum, int nb, int* rowptr, int N) {
    if (threadIdx.x == 0) {
        int s = 0;
        for (int i = 0; i < nb; ++i) { int v = bsum[i]; bsum[i] = s; s += v; }
        rowptr[N] = s;
    }
}

__global__ __launch_bounds__(1024)
void scan3_kernel(int* __restrict__ rowptr, int* __restrict__ cursor,
                  const int* __restrict__ bsum, int N) {
    int i = blockIdx.x * 1024 + threadIdx.x;
    if (i < N) {
        int v = rowptr[i] + bsum[blockIdx.x];
        rowptr[i] = v;
        cursor[i] = v;
    }
}

__global__ __launch_bounds__(256)
void fill_csr_kernel(const int* __restrict__ row, const int* __restrict__ col,
                     int* __restrict__ cursor, int* __restrict__ csr_src, int E) {
    int e = blockIdx.x * 256 + threadIdx.x;
    if (e < E) {
        int pos = atomicAdd(&cursor[col[e]], 1);
        csr_src[pos] = row[e];
    }
}

__global__ __launch_bounds__(1024)
void goff_kernel(const int* __restrict__ nn, int* __restrict__ goff, double* kl_acc) {
    __shared__ int sh[1024];
    __shared__ int carry;
    int t = threadIdx.x;
    if (t == 0) carry = 0;
    __syncthreads();
    for (int base = 0; base < BB; base += 1024) {
        int v = nn[base + t];
        sh[t] = v; __syncthreads();
        for (int o = 1; o < 1024; o <<= 1) {
            int x = (t >= o) ? sh[t - o] : 0;
            __syncthreads();
            sh[t] += x;
            __syncthreads();
        }
        goff[base + t] = carry + sh[t] - v;
        int tot = sh[1023];
        __syncthreads();
        if (t == 0) carry += tot;
        __syncthreads();
    }
    if (t == 0) { goff[BB] = carry; *kl_acc = 0.0; }
}

// ---------------------------------------------------------------------------
// merged pad-vector prep
// ---------------------------------------------------------------------------
__global__ __launch_bounds__(256)
void pads_kernel(const float* b1, const float* b2, const float* b3,
                 const float* seg, const float* mb1, const float* vb1,
                 float* b1p, float* b2p, float* b3p, float* segp, float* b768p) {
    int i = blockIdx.x * 256 + threadIdx.x;
    if (i < 192)            b1p[i] = (i < 188) ? b1[i] : 0.0f;
    else if (i < 480)  { int j = i - 192;  b2p[j]   = (j < 282) ? b2[j]  : 0.0f; }
    else if (i < 864)  { int j = i - 480;  b3p[j]   = (j < 376) ? b3[j]  : 0.0f; }
    else if (i < 1248) { int j = i - 864;  segp[j]  = (j < 376) ? seg[j] : 0.0f; }
    else if (i < 1632) { int j = i - 1248; b768p[j] = (j < 376) ? mb1[j] : 0.0f; }
    else if (i < 2016) { int j = i - 1632; b768p[384 + j] = (j < 376) ? vb1[j] : 0.0f; }
}

__global__ __launch_bounds__(256)
void init_bias_kernel(float* __restrict__ out, const float* __restrict__ bias,
                      size_t total, int F) {
    size_t idx = (size_t)blockIdx.x * 256 + threadIdx.x;
    if (idx < total) out[idx] = bias[idx % F];
}

__global__ __launch_bounds__(256)
void cast4_kernel(const float4* __restrict__ in, u16x4* __restrict__ out, int total4) {
    int idx = blockIdx.x * 256 + threadIdx.x;
    if (idx >= total4) return;
    float4 v = in[idx];
    u16x4 o; o.x = f2bf(v.x); o.y = f2bf(v.y); o.z = f2bf(v.z); o.w = f2bf(v.w);
    out[idx] = o;
}

// ---------------------------------------------------------------------------
// batched weight transpose+cast
// ---------------------------------------------------------------------------
constexpr int NJOBS = 10;
struct TJobs {
    const float* W[NJOBS];
    u16* out[NJOBS];
    int K[NJOBS], Nn[NJOBS], base[NJOBS], ktiles[NJOBS];
    int njobs;
};

__global__ __launch_bounds__(256)
void transpose_batch_kernel(TJobs jobs) {
    __shared__ float t[32][33];
    int tb = blockIdx.x;
    int j = 0;
    #pragma unroll
    for (int i = 1; i < NJOBS; ++i)
        if (i < jobs.njobs && tb >= jobs.base[i]) j = i;
    int rel = tb - jobs.base[j];
    int gk = (rel % jobs.ktiles[j]) * 32;
    int gn = (rel / jobs.ktiles[j]) * 32;
    const float* W = jobs.W[j];
    u16* out = jobs.out[j];
    int K = jobs.K[j], Nn = jobs.Nn[j];
    int Kpad = jobs.ktiles[j] * 32;

    int tx = threadIdx.x & 31, ty = threadIdx.x >> 5;
    #pragma unroll
    for (int r = 0; r < 4; ++r) {
        int row = gk + ty + r * 8, col = gn + tx;
        t[ty + r * 8][tx] = (row < K && col < Nn) ? W[(size_t)row * Nn + col] : 0.0f;
    }
    __syncthreads();
    #pragma unroll
    for (int r = 0; r < 4; ++r) {
        int n = gn + ty + r * 8, k = gk + tx;
        out[(size_t)n * Kpad + k] = f2bf(t[tx][ty + r * 8]);
    }
}

// ---------------------------------------------------------------------------
// aggregate-first GCN sparse step
// ---------------------------------------------------------------------------
template<int U, int G, bool F32IN>
__global__ __launch_bounds__(256)
void agg_kernel(const void* __restrict__ inp, const int* __restrict__ rowptr,
                const int* __restrict__ csr_src, const float* __restrict__ dinv,
                u16* __restrict__ out, int N) {
    constexpr int NPB = 256 / G;
    int u = threadIdx.x & (G - 1);
    int n = blockIdx.x * NPB + threadIdx.x / G;
    if (n >= N || u >= U) return;
    float di = dinv[n];
    float acc[8];
    if (F32IN) {
        const float* xr = (const float*)inp + (size_t)n * 94 + u * 8;
        #pragma unroll
        for (int j = 0; j < 8; ++j)
            acc[j] = (u * 8 + j < 94) ? di * xr[j] : 0.0f;
    } else {
        float t[8];
        unpack8(((const uint4*)inp)[(size_t)n * U + u], t);
        #pragma unroll
        for (int j = 0; j < 8; ++j) acc[j] = di * t[j];
    }
    int e0 = rowptr[n], e1 = rowptr[n + 1];
    for (int e = e0; e < e1; ++e) {
        int r = csr_src[e];
        float w = dinv[r];
        if (F32IN) {
            const float* rr = (const float*)inp + (size_t)r * 94 + u * 8;
            #pragma unroll
            for (int j = 0; j < 8; ++j)
                if (u * 8 + j < 94) acc[j] = fmaf(w, rr[j], acc[j]);
        } else {
            float t[8];
            unpack8(((const uint4*)inp)[(size_t)r * U + u], t);
            #pragma unroll
            for (int j = 0; j < 8; ++j) acc[j] = fmaf(w, t[j], acc[j]);
        }
    }
    unsigned w0 = (unsigned)f2bf(di * acc[0]) | ((unsigned)f2bf(di * acc[1]) << 16);
    unsigned w1 = (unsigned)f2bf(di * acc[2]) | ((unsigned)f2bf(di * acc[3]) << 16);
    unsigned w2 = (unsigned)f2bf(di * acc[4]) | ((unsigned)f2bf(di * acc[5]) << 16);
    unsigned w3 = (unsigned)f2bf(di * acc[6]) | ((unsigned)f2bf(di * acc[7]) << 16);
    ((uint4*)out)[(size_t)n * U + u] = make_uint4(w0, w1, w2, w3);
}

// ---------------------------------------------------------------------------
// A-panel-resident GEMM (layer GEMMs)
// MODE: 2 bf16 relu(v+bias), 7 L3 epilogue (a0b + dseq scatter)
// ---------------------------------------------------------------------------
template<int MODE, int KP>
__global__ __launch_bounds__(256)
void panel_gemm_kernel(const u16* __restrict__ A, const u16* __restrict__ BT,
                       const float* __restrict__ bias, void* __restrict__ Cout,
                       int M, int Nn, int lda, int ldb, int Ldc, int NallocB,
                       const float* __restrict__ segp, const int* __restrict__ posv,
                       const int* __restrict__ batchv, float* __restrict__ dseq) {
    constexpr int U   = KP / 8;
    constexpr int STR = (U + 1) * 16;
    constexpr int NK  = KP / 32;
    __shared__ __align__(16) char lds[64 * STR];

    const int tid  = threadIdx.x;
    const int lid  = tid & 63;
    const int wave = tid >> 6;
    const int wc   = wave * 64;
    const int bm   = blockIdx.x * 64;

    #pragma unroll
    for (int s = tid; s < 64 * U; s += 256) {
        int row = s / U, u = s - row * U;
        int ra = bm + row; if (ra >= M) ra = M - 1;
        *(uint4*)(&lds[row * STR + u * 16]) =
            *(const uint4*)(A + (size_t)ra * lda + u * 8);
    }
    __syncthreads();

    const int ku  = lid >> 4;
    const int rlo = lid & 15;
    const char* aBase = &lds[rlo * STR + ku * 16];

    u16* Cb = (u16*)Cout;

    const int nchunks = (NallocB + 255) >> 8;
    for (int nc = 0; nc < nchunks; ++nc) {
        const int bn = nc * 256 + wc;
        if (bn >= NallocB) continue;

        const u16* bp[4];
        #pragma unroll
        for (int j = 0; j < 4; ++j) {
            int br = bn + j * 16 + rlo;
            if (br > NallocB - 1) br = NallocB - 1;
            bp[j] = BT + (size_t)br * ldb + ku * 8;
        }

        f32x4 acc[4][4];
        #pragma unroll
        for (int i = 0; i < 4; ++i)
            #pragma unroll
            for (int j = 0; j < 4; ++j)
                acc[i][j] = (f32x4){0.0f, 0.0f, 0.0f, 0.0f};

        bf16x8 b0[4], b1[4];
        #pragma unroll
        for (int j = 0; j < 4; ++j) b0[j] = *(const bf16x8*)(bp[j]);
        if (NK > 1) {
            #pragma unroll
            for (int j = 0; j < 4; ++j) b1[j] = *(const bf16x8*)(bp[j] + 32);
        }

        #pragma unroll
        for (int t = 0; t < NK; ++t) {
            bf16x8 a[4];
            #pragma unroll
            for (int i = 0; i < 4; ++i)
                a[i] = *(const bf16x8*)(aBase + i * 16 * STR + t * 64);
            bf16x8 b2[4];
            if (t + 2 < NK) {
                #pragma unroll
                for (int j = 0; j < 4; ++j)
                    b2[j] = *(const bf16x8*)(bp[j] + (t + 2) * 32);
            }
            #pragma unroll
            for (int i = 0; i < 4; ++i)
                #pragma unroll
                for (int j = 0; j < 4; ++j)
                    acc[i][j] = __builtin_amdgcn_mfma_f32_16x16x32_bf16(a[i], b0[j], acc[i][j], 0, 0, 0);
            #pragma unroll
            for (int j = 0; j < 4; ++j) { b0[j] = b1[j]; b1[j] = b2[j]; }
        }

        const int nlim = (MODE == 7) ? Ldc : Nn;
        #pragma unroll
        for (int i = 0; i < 4; ++i) {
            #pragma unroll
            for (int r = 0; r < 4; ++r) {
                int m = bm + i * 16 + ku * 4 + r;
                if (m >= M) continue;
                size_t drow = 0;
                if (MODE == 7)
                    drow = ((size_t)posv[m] * BB + batchv[m]) * (size_t)HH;
                #pragma unroll
                for (int j = 0; j < 4; ++j) {
                    int n = bn + j * 16 + rlo;
                    if (n >= nlim) continue;
                    float v = acc[i][j][r];
                    if (MODE == 2)      Cb[(size_t)m * Ldc + n] = f2bf(fmaxf(v + bias[n], 0.0f));
                    else if (MODE == 7) {
                        float h = fmaxf(v + bias[n], 0.0f);
                        float d = h + segp[n];
                        Cb[(size_t)m * Ldc + n] = f2bf(d);
                        if (n < Nn) dseq[drow + n] = d;
                    }
                }
            }
        }
    }
}

template<int MODE, int KP>
static void pgemm(hipStream_t s, const u16* A, const u16* BT, const float* bias,
                  void* C, int M, int Nn, int lda, int ldb, int Ldc, int NallocB,
                  const float* segp = nullptr, const int* posv = nullptr,
                  const int* batchv = nullptr, float* dseq = nullptr) {
    panel_gemm_kernel<MODE, KP><<<cdiv(M, 64), 256, 0, s>>>(
        A, BT, bias, C, M, Nn, lda, ldb, Ldc, NallocB, segp, posv, batchv, dseq);
}

// ---------------------------------------------------------------------------
// FUSED mu/logvar chain — merged K-halves: full t1 (64x384) in LDS,
// 2 barriers per part instead of 4; acc1/acc2 never simultaneously live.
// ---------------------------------------------------------------------------
__global__ __launch_bounds__(384)
void muvar_kernel(const u16* __restrict__ a0, const u16* __restrict__ mv1T,
                  const float* __restrict__ b768p,
                  const u16* __restrict__ mW2T, const u16* __restrict__ vW2T,
                  const float* __restrict__ mb2, const float* __restrict__ vb2,
                  u16* __restrict__ mu_b, u16* __restrict__ zlv_b, int M) {
    constexpr int UA = 48, STRA = (UA + 1) * 16;   // a0 row stride 784 B
    constexpr int STRT = 49 * 16;                  // t1 row stride 784 B (392 cols)
    __shared__ __align__(16) char Alds[64 * STRA]; // 50176 B
    __shared__ __align__(16) char Tlds[64 * STRT]; // 50176 B (total ~100 KB)

    const int tid  = threadIdx.x;
    const int lid  = tid & 63;
    const int wave = tid >> 6;          // 0..5
    const int bm   = blockIdx.x * 64;
    const int ku   = lid >> 4;
    const int rlo  = lid & 15;

    for (int s = tid; s < 64 * UA; s += 384) {
        int row = s / UA, u = s - row * UA;
        int ra = bm + row; if (ra >= M) ra = M - 1;
        *(uint4*)(&Alds[row * STRA + u * 16]) =
            *(const uint4*)(a0 + (size_t)ra * 384 + u * 8);
    }
    __syncthreads();

    const char* aBase1 = &Alds[rlo * STRA + ku * 16];
    const char* aBase2 = &Tlds[rlo * STRT + ku * 16];

    #pragma unroll 1
    for (int part = 0; part < 2; ++part) {
        const u16* B2 = part ? vW2T : mW2T;

        // ---- GEMM1: t1(64x384) = relu(a0 @ W1cols + bias); wave owns 64 cols
        {
            const u16* bp1[4];
            #pragma unroll
            for (int j = 0; j < 4; ++j) {
                int br = part * 384 + wave * 64 + j * 16 + rlo;
                bp1[j] = mv1T + (size_t)br * 384 + ku * 8;
            }
            f32x4 acc1[4][4];
            #pragma unroll
            for (int i = 0; i < 4; ++i)
                #pragma unroll
                for (int j = 0; j < 4; ++j)
                    acc1[i][j] = (f32x4){0.0f, 0.0f, 0.0f, 0.0f};

            bf16x8 cq[4][4];
            #pragma unroll
            for (int d = 0; d < 4; ++d)
                #pragma unroll
                for (int j = 0; j < 4; ++j)
                    cq[d][j] = *(const bf16x8*)(bp1[j] + d * 32);

            #pragma unroll
            for (int t = 0; t < 12; ++t) {
                bf16x8 a[4];
                #pragma unroll
                for (int i = 0; i < 4; ++i)
                    a[i] = *(const bf16x8*)(aBase1 + i * 16 * STRA + t * 64);
                bf16x8 cur[4];
                #pragma unroll
                for (int j = 0; j < 4; ++j) cur[j] = cq[t & 3][j];
                if (t + 4 < 12) {
                    #pragma unroll
                    for (int j = 0; j < 4; ++j)
                        cq[t & 3][j] = *(const bf16x8*)(bp1[j] + (t + 4) * 32);
                }
                #pragma unroll
                for (int i = 0; i < 4; ++i)
                    #pragma unroll
                    for (int j = 0; j < 4; ++j)
                        acc1[i][j] = __builtin_amdgcn_mfma_f32_16x16x32_bf16(a[i], cur[j], acc1[i][j], 0, 0, 0);
            }

            // write t1 (relu + bias) into Tlds as bf16 rows [64][384]
            #pragma unroll
            for (int i = 0; i < 4; ++i) {
                #pragma unroll
                for (int r = 0; r < 4; ++r) {
                    int m = i * 16 + ku * 4 + r;
                    #pragma unroll
                    for (int j = 0; j < 4; ++j) {
                        int n = wave * 64 + j * 16 + rlo;
                        float v = fmaxf(acc1[i][j][r] + b768p[part * 384 + n], 0.0f);
                        *(u16*)(&Tlds[m * STRT + n * 2]) = f2bf(v);
                    }
                }
            }
        }
        __syncthreads();

        // ---- GEMM2: out = t1 @ W2 (K=384 in one pass); wave owns 64 cols
        f32x4 acc2[4][4];
        #pragma unroll
        for (int i = 0; i < 4; ++i)
            #pragma unroll
            for (int j = 0; j < 4; ++j)
                acc2[i][j] = (f32x4){0.0f, 0.0f, 0.0f, 0.0f};
        {
            const u16* bp2[4];
            #pragma unroll
            for (int j = 0; j < 4; ++j) {
                int br = wave * 64 + j * 16 + rlo;
                if (br > 383) br = 383;
                bp2[j] = B2 + (size_t)br * 384 + ku * 8;
            }
            bf16x8 dq[4][4];
            #pragma unroll
            for (int d = 0; d < 4; ++d)
                #pragma unroll
                for (int j = 0; j < 4; ++j)
                    dq[d][j] = *(const bf16x8*)(bp2[j] + d * 32);

            #pragma unroll
            for (int t = 0; t < 12; ++t) {
                bf16x8 a[4];
                #pragma unroll
                for (int i = 0; i < 4; ++i)
                    a[i] = *(const bf16x8*)(aBase2 + i * 16 * STRT + t * 64);
                bf16x8 cur[4];
                #pragma unroll
                for (int j = 0; j < 4; ++j) cur[j] = dq[t & 3][j];
                if (t + 4 < 12) {
                    #pragma unroll
                    for (int j = 0; j < 4; ++j)
                        dq[t & 3][j] = *(const bf16x8*)(bp2[j] + (t + 4) * 32);
                }
                #pragma unroll
                for (int i = 0; i < 4; ++i)
                    #pragma unroll
                    for (int j = 0; j < 4; ++j)
                        acc2[i][j] = __builtin_amdgcn_mfma_f32_16x16x32_bf16(a[i], cur[j], acc2[i][j], 0, 0, 0);
            }
        }

        // ---- epilogue: write mu (part 0) / zlv (part 1), bf16 compact [N][376]
        u16* outp = part ? zlv_b : mu_b;
        const float* bias2 = part ? vb2 : mb2;
        #pragma unroll
        for (int i = 0; i < 4; ++i) {
            #pragma unroll
            for (int r = 0; r < 4; ++r) {
                int gm = bm + i * 16 + ku * 4 + r;
                if (gm >= M) continue;
                #pragma unroll
                for (int j = 0; j < 4; ++j) {
                    int n = wave * 64 + j * 16 + rlo;
                    if (n >= 376) continue;
                    float v = acc2[i][j][r] + bias2[n];
                    if (part) v = -fabsf(v);
                    outp[(size_t)gm * 376 + n] = f2bf(v);
                }
            }
        }
        __syncthreads();   // before next part overwrites Tlds
    }
}

// ---------------------------------------------------------------------------
// classic tiled MFMA GEMM (con / fc1 / fc2)
// MODE: 2 bf16 relu(v+bias) pad-zeroed, 3 f32 atomicAdd
// ---------------------------------------------------------------------------
__device__ __forceinline__ int lds_swz(int row, int u) {
    return u ^ (row & 3) ^ ((row >> 2) & 3);
}

template<int MODE>
__global__ __launch_bounds__(256)
void mfma_gemm_kernel(const u16* __restrict__ A, const u16* __restrict__ BT,
                      const float* __restrict__ bias, void* __restrict__ Cout,
                      int M, int Nn, int KA, int lda, int ldb, int Ldc,
                      int NallocB, int Kchunk) {
    __shared__ uint4 As[2][512];
    __shared__ uint4 Bs[2][512];

    const int tid  = threadIdx.x;
    const int lid  = tid & 63;
    const int wave = tid >> 6;
    const int wr   = (wave >> 1) * 64;
    const int wc   = (wave & 1) * 64;
    const int bn   = blockIdx.x * 128;
    const int bm   = blockIdx.y * 128;
    const int k0   = blockIdx.z * Kchunk;
    const int k1   = min(KA, k0 + Kchunk);
    const int nt   = (k1 - k0) >> 5;

    int wb[2];
    const u16* gA[2];
    const u16* gB[2];
    #pragma unroll
    for (int it = 0; it < 2; ++it) {
        int s = tid + it * 256;
        int row = s >> 2, u = s & 3;
        wb[it] = row * 4 + lds_swz(row, u);
        int ra = bm + row; ra = ra < M ? ra : M - 1;
        int rb = bn + row; rb = rb < NallocB ? rb : NallocB - 1;
        gA[it] = A  + (size_t)ra * lda + u * 8;
        gB[it] = BT + (size_t)rb * ldb + u * 8;
    }

    f32x4 acc[4][4];
    #pragma unroll
    for (int i = 0; i < 4; ++i)
        #pragma unroll
        for (int j = 0; j < 4; ++j)
            acc[i][j] = (f32x4){0.0f, 0.0f, 0.0f, 0.0f};

    uint4 sa[2], sb[2];
    #pragma unroll
    for (int it = 0; it < 2; ++it) {
        sa[it] = *(const uint4*)(gA[it] + k0);
        sb[it] = *(const uint4*)(gB[it] + k0);
    }
    As[0][wb[0]] = sa[0]; As[0][wb[1]] = sa[1];
    Bs[0][wb[0]] = sb[0]; Bs[0][wb[1]] = sb[1];
    if (nt > 1) {
        #pragma unroll
        for (int it = 0; it < 2; ++it) {
            sa[it] = *(const uint4*)(gA[it] + k0 + 32);
            sb[it] = *(const uint4*)(gB[it] + k0 + 32);
        }
    }

    const int ku  = lid >> 4;
    const int rlo = lid & 15;

    for (int t = 0; t < nt; ++t) {
        __syncthreads();
        const int cur = t & 1;
        if (t + 1 < nt) {
            const int nxt = cur ^ 1;
            As[nxt][wb[0]] = sa[0]; As[nxt][wb[1]] = sa[1];
            Bs[nxt][wb[0]] = sb[0]; Bs[nxt][wb[1]] = sb[1];
        }
        bf16x8 aF[4], bF[4];
        #pragma unroll
        for (int i = 0; i < 4; ++i) {
            int row = wr + i * 16 + rlo;
            aF[i] = *(const bf16x8*)&As[cur][row * 4 + lds_swz(row, ku)];
        }
        #pragma unroll
        for (int j = 0; j < 4; ++j) {
            int row = wc + j * 16 + rlo;
            bF[j] = *(const bf16x8*)&Bs[cur][row * 4 + lds_swz(row, ku)];
        }
        if (t + 2 < nt) {
            int kk = k0 + (t + 2) * 32;
            #pragma unroll
            for (int it = 0; it < 2; ++it) {
                sa[it] = *(const uint4*)(gA[it] + kk);
                sb[it] = *(const uint4*)(gB[it] + kk);
            }
        }
        #pragma unroll
        for (int i = 0; i < 4; ++i)
            #pragma unroll
            for (int j = 0; j < 4; ++j)
                acc[i][j] = __builtin_amdgcn_mfma_f32_16x16x32_bf16(aF[i], bF[j], acc[i][j], 0, 0, 0);
    }

    float* Cf = (float*)Cout;
    u16*   Cb = (u16*)Cout;
    const int rq = lid >> 4;
    #pragma unroll
    for (int i = 0; i < 4; ++i) {
        #pragma unroll
        for (int r = 0; r < 4; ++r) {
            int m = bm + wr + i * 16 + rq * 4 + r;
            if (m >= M) continue;
            #pragma unroll
            for (int j = 0; j < 4; ++j) {
                int n = bn + wc + j * 16 + rlo;
                float v = acc[i][j][r];
                if (MODE == 3) {
                    if (n < Nn) atomicAdd(&Cf[(size_t)m * Ldc + n], v);
                } else if (MODE == 2) {
                    if (n < Ldc) {
                        float o = 0.0f;
                        if (n < Nn) o = fmaxf(v + (bias ? bias[n] : 0.0f), 0.0f);
                        Cb[(size_t)m * Ldc + n] = f2bf(o);
                    }
                }
            }
        }
    }
}

template<int MODE>
static void mgemm(hipStream_t s, const u16* A, const u16* BT, const float* bias,
                  void* C, int M, int Nn, int KA, int lda, int ldb, int Ldc,
                  int NallocB, int splitk) {
    int ncols = (MODE == 2) ? Ldc : Nn;
    dim3 grid(cdiv(ncols, 128), cdiv(M, 128), splitk);
    int Kchunk = (cdiv(KA, splitk) + 31) & ~31;
    mfma_gemm_kernel<MODE><<<grid, 256, 0, s>>>(A, BT, bias, C, M, Nn, KA, lda, ldb,
                                                Ldc, NallocB, Kchunk);
}

// ---------------------------------------------------------------------------
// pad rows of d_seq + mask (merged)
// ---------------------------------------------------------------------------
__global__ __launch_bounds__(256)
void dseq_pad_mask_kernel(const float* __restrict__ seg, const int* __restrict__ nn,
                          float4* __restrict__ out, float* __restrict__ out_mask) {
    int idx = blockIdx.x * 256 + threadIdx.x;
    if (idx < BB * LL) {
        int b = idx / LL, l = idx % LL;
        out_mask[idx] = (l >= nn[b]) ? 1.0f : 0.0f;
    }
    if (idx >= LL * BB * 94) return;
    int k4 = idx % 94;
    int rowi = idx / 94;
    int b = rowi & (BB - 1);
    int l = rowi >> 11;
    if (l < nn[b]) return;
    float4 s4 = ((const float4*)seg)[k4];
    float4 o; o.x = PADV + s4.x; o.y = PADV + s4.y; o.z = PADV + s4.z; o.w = PADV + s4.w;
    out[idx] = o;
}

// ---------------------------------------------------------------------------
// pad-row mu/zlv + exact pad kl contribution (fp32)
// ---------------------------------------------------------------------------
__global__ __launch_bounds__(384)
void pad_vec_kernel(const float* __restrict__ seg,
                    const float* __restrict__ mW1, const float* __restrict__ mb1,
                    const float* __restrict__ mW2, const float* __restrict__ mb2,
                    const float* __restrict__ vW1, const float* __restrict__ vb1,
                    const float* __restrict__ vW2, const float* __restrict__ vb2,
                    float* __restrict__ mu_pad, float* __restrict__ zlv_pad,
                    double* kl_acc, int n_pad_rows) {
    __shared__ float t1[HH], t2[HH], red[HH];
    int j = threadIdx.x;
    if (j < HH) {
        float s1 = mb1[j], s2 = vb1[j];
        for (int k = 0; k < HH; ++k) {
            float p = PADV + seg[k];
            s1 += p * mW1[k * HH + j];
            s2 += p * vW1[k * HH + j];
        }
        t1[j] = fmaxf(s1, 0.0f);
        t2[j] = fmaxf(s2, 0.0f);
    }
    __syncthreads();
    if (j < HH) {
        float m = mb2[j], v = vb2[j];
        for (int k = 0; k < HH; ++k) {
            m += t1[k] * mW2[k * HH + j];
            v += t2[k] * vW2[k * HH + j];
        }
        float z = -fabsf(v);
        mu_pad[j]  = m;
        zlv_pad[j] = z;
        red[j] = 1.0f + z - m * m - expf(z);
    }
    __syncthreads();
    if (j == 0) {
        double s = 0.0;
        for (int k = 0; k < HH; ++k) s += (double)red[k];
        atomicAdd(kl_acc, s * (double)n_pad_rows);
    }
}

// ---------------------------------------------------------------------------
// fused amvo + kl(real rows); mu/zlv bf16 compact [N][376]
// ---------------------------------------------------------------------------
__global__ __launch_bounds__(256)
void amvo_kl4_kernel(const u16x4* __restrict__ mu, const u16x4* __restrict__ zlv,
                     const float* __restrict__ mu_pad, const float* __restrict__ zlv_pad,
                     const float* __restrict__ con_emb, const float* __restrict__ aff,
                     const float4* __restrict__ eps4,
                     const int* __restrict__ nn, const int* __restrict__ goff,
                     float4* __restrict__ out, float* __restrict__ kl_part) {
    const int T4 = LL * BB * 94;
    float kls = 0.0f;
    for (int idx = blockIdx.x * 256 + threadIdx.x; idx < T4; idx += 2048 * 256) {
        int k4 = idx % 94;
        int rowi = idx / 94;
        int b = rowi & (BB - 1);
        int l = rowi >> 11;
        float4 m, z;
        if (l < nn[b]) {
            size_t o = (size_t)(goff[b] + l) * 94 + k4;
            u16x4 mm = mu[o], zz = zlv[o];
            m.x = bf2f(mm.x); m.y = bf2f(mm.y); m.z = bf2f(mm.z); m.w = bf2f(mm.w);
            z.x = bf2f(zz.x); z.y = bf2f(zz.y); z.z = bf2f(zz.z); z.w = bf2f(zz.w);
            kls += (1.0f + z.x - m.x * m.x - __expf(z.x))
                 + (1.0f + z.y - m.y * m.y - __expf(z.y))
                 + (1.0f + z.z - m.z * m.z - __expf(z.z))
                 + (1.0f + z.w - m.w * m.w - __expf(z.w));
        } else {
            m = ((const float4*)mu_pad)[k4];
            z = ((const float4*)zlv_pad)[k4];
        }
        float4 e = eps4[idx];
        float4 c = ((const float4*)con_emb)[(size_t)b * 94 + k4];
        float af = aff[b];
        float4 o;
        o.x = m.x + __expf(0.5f * z.x) * e.x + c.x + af;
        o.y = m.y + __expf(0.5f * z.y) * e.y + c.y + af;
        o.z = m.z + __expf(0.5f * z.z) * e.z + c.z + af;
        o.w = m.w + __expf(0.5f * z.w) * e.w + c.w + af;
        out[idx] = o;
    }
    __shared__ float red[256];
    red[threadIdx.x] = kls;
    __syncthreads();
    for (int s = 128; s > 0; s >>= 1) {
        if (threadIdx.x < s) red[threadIdx.x] += red[threadIdx.x + s];
        __syncthreads();
    }
    if (threadIdx.x == 0) kl_part[blockIdx.x] = red[0];
}

__global__ __launch_bounds__(256)
void kl_final_kernel(const float* __restrict__ kl_part, int nparts,
                     const double* __restrict__ kl_acc, float* __restrict__ out) {
    __shared__ double red[256];
    double s = 0.0;
    for (int i = threadIdx.x; i < nparts; i += 256) s += (double)kl_part[i];
    red[threadIdx.x] = s;
    __syncthreads();
    for (int st = 128; st > 0; st >>= 1) {
        if (threadIdx.x < st) red[threadIdx.x] += red[threadIdx.x + st];
        __syncthreads();
    }
    if (threadIdx.x == 0) out[0] = (float)(-0.5 * (red[0] + *kl_acc) / 64.0);
}

// ---------------------------------------------------------------------------
// global max pool from a0b (= bf16(h3+seg)): x2 = max(a0b) - seg
// ---------------------------------------------------------------------------
__global__ __launch_bounds__(384)
void pool_kernel(const u16* __restrict__ a0b, const float* __restrict__ segp,
                 const int* __restrict__ goff, const int* __restrict__ nn,
                 u16* __restrict__ x2b) {
    int b = blockIdx.x;
    int f = threadIdx.x;
    float m = 0.0f;
    if (f < HH) {
        int off = goff[b], sz = nn[b];
        float mx = -1e30f;
        for (int l = 0; l < sz; ++l)
            mx = fmaxf(mx, bf2f(a0b[(size_t)(off + l) * 384 + f]));
        m = mx - segp[f];
    }
    x2b[(size_t)b * 384 + f] = f2bf(m);
}

// ---------------------------------------------------------------------------
extern "C" void kernel_launch(void* const* d_in, const int* in_sizes, int n_in,
                              void* d_out, int out_size, void* d_ws, size_t ws_size,
                              hipStream_t stream) {
    const float* x      = (const float*)d_in[0];
    const float* con    = (const float*)d_in[1];
    const float* aff    = (const float*)d_in[2];
    const float* eps    = (const float*)d_in[3];
    const int*   eidx   = (const int*)  d_in[4];
    const int*   batch  = (const int*)  d_in[5];
    const int*   nn     = (const int*)  d_in[6];
    const int*   pos    = (const int*)  d_in[7];
    const float* seg    = (const float*)d_in[8];
    const float* W1     = (const float*)d_in[9];
    const float* b1     = (const float*)d_in[10];
    const float* W2     = (const float*)d_in[11];
    const float* b2     = (const float*)d_in[12];
    const float* W3     = (const float*)d_in[13];
    const float* b3     = (const float*)d_in[14];
    const float* condW  = (const float*)d_in[15];
    const float* condB  = (const float*)d_in[16];
    const float* mW1    = (const float*)d_in[17];
    const float* mb1    = (const float*)d_in[18];
    const float* mW2    = (const float*)d_in[19];
    const float* mb2    = (const float*)d_in[20];
    const float* vW1    = (const float*)d_in[21];
    const float* vb1    = (const float*)d_in[22];
    const float* vW2    = (const float*)d_in[23];
    const float* vb2    = (const float*)d_in[24];
    const float* fc1W   = (const float*)d_in[25];
    const float* fc1b   = (const float*)d_in[26];
    const float* fc2W   = (const float*)d_in[27];
    const float* fc2b   = (const float*)d_in[28];

    const int N = in_sizes[0] / DF_;          // 81725
    const int E = in_sizes[4] / 2;            // 326900
    const int* erow = eidx;
    const int* ecol = eidx + E;
    const int n_pad_rows = LL * BB - N;

    const size_t dseqN = (size_t)LL * BB * HH;
    float* out_dseq = (float*)d_out;
    float* out_amvo = out_dseq + dseqN;
    float* out_mask = out_amvo + dseqN;
    float* out_pmvo = out_mask + (size_t)BB * LL;
    float* out_kl   = out_pmvo + (size_t)BB * FIN;

    // ---- workspace carve ----
    char* p = (char*)d_ws;
    size_t off = 0;
    auto alloc = [&](size_t bytes) -> char* {
        char* q = p + off;
        off = (off + bytes + 255) & ~(size_t)255;
        return q;
    };
    float*  dinv    = (float*) alloc((size_t)N * 4);
    int*    deg     = (int*)   alloc((size_t)N * 4);
    int*    rowptr  = (int*)   alloc((size_t)(N + 1) * 4);
    int*    cursor  = (int*)   alloc((size_t)N * 4);
    int*    csr_src = (int*)   alloc((size_t)E * 4);
    int*    bsum    = (int*)   alloc((size_t)128 * 4);
    int*    goff    = (int*)   alloc((size_t)(BB + 1) * 4);
    float*  mu_pad  = (float*) alloc(HH * 4);
    float*  zlv_pad = (float*) alloc(HH * 4);
    double* kl_acc  = (double*)alloc(8);
    float*  kl_part = (float*) alloc(2048 * 4);
    float*  b1p     = (float*) alloc(192 * 4);
    float*  b2p     = (float*) alloc(288 * 4);
    float*  b3p     = (float*) alloc(384 * 4);
    float*  segp    = (float*) alloc(384 * 4);
    float*  b768p   = (float*) alloc(768 * 4);
    float*  con_emb = (float*) alloc((size_t)BB * HH * 4);
    u16*    x2b     = (u16*)   alloc((size_t)BB * 384 * 2);
    u16*    tfcb    = (u16*)   alloc((size_t)BB * 1024 * 2);
    u16*    W1T     = (u16*)   alloc((size_t)192 * 96 * 2);
    u16*    W2T     = (u16*)   alloc((size_t)288 * 192 * 2);
    u16*    W3T     = (u16*)   alloc((size_t)384 * 288 * 2);
    u16*    mv1T    = (u16*)   alloc((size_t)768 * 384 * 2);   // [mW1T;vW1T]
    u16*    mW2T    = (u16*)   alloc((size_t)384 * 384 * 2);
    u16*    vW2T    = (u16*)   alloc((size_t)384 * 384 * 2);
    u16*    condWT  = (u16*)   alloc((size_t)384 * 10272 * 2);
    u16*    fc1WT   = (u16*)   alloc((size_t)1024 * 384 * 2);
    u16*    fc2WT   = (u16*)   alloc((size_t)256 * 1024 * 2);
    u16*    a0b     = (u16*)   alloc((size_t)N * 384 * 2);     // bf16(h3+seg) padded
    u16*    mu_b    = (u16*)   alloc((size_t)N * 376 * 2);
    u16*    zlv_b   = (u16*)   alloc((size_t)N * 376 * 2);
    u16*    aggb    = (u16*)   alloc((size_t)N * 288 * 2);
    u16*    actb    = (u16*)   alloc((size_t)N * 288 * 2);

    // bf16 scratch in the (not-yet-written) amvo output region
    char* q = (char*)out_amvo;
    size_t qoff = 0;
    auto qalloc = [&](size_t bytes) -> char* {
        char* r = q + qoff;
        qoff = (qoff + bytes + 255) & ~(size_t)255;
        return r;
    };
    u16* conb = (u16*)qalloc((size_t)BB * 10272 * 2);   // 42 MB
    (void)ws_size; (void)n_in; (void)out_size;

    // ---- degree / dinv / CSR / goff ----
    const int NB = cdiv(N, 1024);
    zero_int_kernel<<<cdiv(N, 256), 256, 0, stream>>>(deg, N);
    count_deg_kernel<<<cdiv(E, 256), 256, 0, stream>>>(ecol, deg, E);
    dinv_kernel<<<cdiv(N, 256), 256, 0, stream>>>(deg, dinv, N);
    scan1_kernel<<<NB, 1024, 0, stream>>>(deg, N, rowptr, bsum);
    scan2_kernel<<<1, 64, 0, stream>>>(bsum, NB, rowptr, N);
    scan3_kernel<<<NB, 1024, 0, stream>>>(rowptr, cursor, bsum, N);
    fill_csr_kernel<<<cdiv(E, 256), 256, 0, stream>>>(erow, ecol, cursor, csr_src, E);
    goff_kernel<<<1, 1024, 0, stream>>>(nn, goff, kl_acc);

    // ---- padded bias / seg vectors ----
    pads_kernel<<<8, 256, 0, stream>>>(b1, b2, b3, seg, mb1, vb1,
                                       b1p, b2p, b3p, segp, b768p);

    // ---- batched weight transposes ----
    {
        TJobs J; J.njobs = NJOBS;
        const float* Ws[NJOBS] = {W1, W2, W3, mW1, vW1, mW2, vW2, condW, fc1W, fc2W};
        u16* Os[NJOBS] = {W1T, W2T, W3T, mv1T, mv1T + 384 * 384, mW2T, vW2T,
                          condWT, fc1WT, fc2WT};
        int Ks[NJOBS]  = {94, 188, 282, 376, 376, 376, 376, 10272, 376, 1024};
        int Ns[NJOBS]  = {188, 282, 376, 376, 376, 376, 376, 376, 1024, 256};
        int Kp[NJOBS]  = {96, 192, 288, 384, 384, 384, 384, 10272, 384, 1024};
        int Np[NJOBS]  = {192, 288, 384, 384, 384, 384, 384, 384, 1024, 256};
        int base = 0;
        for (int i = 0; i < NJOBS; ++i) {
            J.W[i] = Ws[i]; J.out[i] = Os[i]; J.K[i] = Ks[i]; J.Nn[i] = Ns[i];
            J.ktiles[i] = Kp[i] / 32;
            J.base[i] = base;
            base += (Kp[i] / 32) * (Np[i] / 32);
        }
        transpose_batch_kernel<<<base, 256, 0, stream>>>(J);
    }

    cast4_kernel<<<cdiv(BB * 10272 / 4, 256), 256, 0, stream>>>(
        (const float4*)con, (u16x4*)conb, BB * 10272 / 4);

    // ---- GCN layer 1 (aggregate-first) ----
    agg_kernel<12, 16, true><<<cdiv(N, 16), 256, 0, stream>>>(
        x, rowptr, csr_src, dinv, aggb, N);
    pgemm<2, 96>(stream, aggb, W1T, b1p, actb, N, 192, 96, 96, 192, 192);

    // ---- GCN layer 2 ----
    agg_kernel<24, 32, false><<<cdiv(N, 8), 256, 0, stream>>>(
        actb, rowptr, csr_src, dinv, aggb, N);
    pgemm<2, 192>(stream, aggb, W2T, b2p, actb, N, 288, 192, 192, 288, 288);

    // ---- GCN layer 3: agg -> gemm with fused a0b/dseq epilogue ----
    agg_kernel<36, 64, false><<<cdiv(N, 4), 256, 0, stream>>>(
        actb, rowptr, csr_src, dinv, aggb, N);
    pgemm<7, 288>(stream, aggb, W3T, b3p, a0b, N, 376, 288, 288, 384, 384,
                  segp, pos, batch, out_dseq);

    // ---- dseq pad rows + mask (merged) / pool ----
    dseq_pad_mask_kernel<<<cdiv(LL * BB * 94, 256), 256, 0, stream>>>(
        seg, nn, (float4*)out_dseq, out_mask);
    pool_kernel<<<BB, 384, 0, stream>>>(a0b, segp, goff, nn, x2b);

    // ---- FUSED mu/logvar chain (merged K-halves, 2 barriers/part) ----
    muvar_kernel<<<cdiv(N, 64), 384, 0, stream>>>(
        a0b, mv1T, b768p, mW2T, vW2T, mb2, vb2, mu_b, zlv_b, N);

    pad_vec_kernel<<<1, 384, 0, stream>>>(seg, mW1, mb1, mW2, mb2, vW1, vb1, vW2, vb2,
                                          mu_pad, zlv_pad, kl_acc, n_pad_rows);

    // ---- conditioning embedding ----
    init_bias_kernel<<<cdiv(BB * HH, 256), 256, 0, stream>>>(con_emb, condB, (size_t)BB * HH, HH);
    mgemm<3>(stream, conb, condWT, nullptr, con_emb, BB, 376, 10272, 10272, 10272, 376, 384, 16);

    // ---- amvo + kl ----
    amvo_kl4_kernel<<<2048, 256, 0, stream>>>((const u16x4*)mu_b, (const u16x4*)zlv_b,
                                              mu_pad, zlv_pad, con_emb, aff,
                                              (const float4*)eps, nn, goff,
                                              (float4*)out_amvo, kl_part);
    kl_final_kernel<<<1, 256, 0, stream>>>(kl_part, 2048, kl_acc, out_kl);

    // ---- pmvo head ----
    mgemm<2>(stream, x2b, fc1WT, fc1b, tfcb, BB, 1024, 384, 384, 384, 1024, 1024, 1);
    init_bias_kernel<<<cdiv(BB * FIN, 256), 256, 0, stream>>>(out_pmvo, fc2b, (size_t)BB * FIN, FIN);
    mgemm<3>(stream, tfcb, fc2WT, nullptr, out_pmvo, BB, 256, 1024, 1024, 1024, 256, 256, 8);
}